// Round 8
// baseline (231.600 us; speedup 1.0000x reference)
//
#include <hip/hip_runtime.h>
#include <hip/hip_bf16.h>

// Problem constants
#define B_ 2
#define S_ 2048
#define D_ 1024
#define H_ 16
#define P_ 2048
#define T_ 4096   // P_ + S_
#define DEPTH_ 64

typedef __bf16 bf16x8 __attribute__((ext_vector_type(8)));
typedef float  f32x4  __attribute__((ext_vector_type(4)));
typedef short  short8_t __attribute__((ext_vector_type(8)));
typedef unsigned short ushort_t;
typedef unsigned short ushort4_t __attribute__((ext_vector_type(4)));

// f32 -> bf16 round-to-nearest-even (cold paths)
__device__ __forceinline__ ushort_t f2bf(float f) {
    union { float f; unsigned u; } v; v.f = f;
    return (ushort_t)((v.u + 0x7fffu + ((v.u >> 16) & 1u)) >> 16);
}

// packed pair f32 -> 2x bf16 in one u32 (hot path; no builtin on gfx950)
__device__ __forceinline__ unsigned cvt_pk_bf16(float lo, float hi) {
    unsigned r;
    asm("v_cvt_pk_bf16_f32 %0, %1, %2" : "=v"(r) : "v"(lo), "v"(hi));
    return r;
}

__device__ __forceinline__ void gload16(const void* g, void* l) {
    __builtin_amdgcn_global_load_lds(
        (const __attribute__((address_space(1))) unsigned int*)g,
        (__attribute__((address_space(3))) unsigned int*)l, 16, 0, 0);
}

// =====================================================================
// x [4096][1024] f32 -> bf16
// =====================================================================
__global__ __launch_bounds__(256)
void convert_bf16_kernel(const float4* __restrict__ in, ushort4_t* __restrict__ out, int n4)
{
    for (int i = blockIdx.x * 256 + threadIdx.x; i < n4; i += gridDim.x * 256) {
        float4 v = in[i];
        ushort4_t o;
        o[0] = f2bf(v.x); o[1] = f2bf(v.y); o[2] = f2bf(v.z); o[3] = f2bf(v.w);
        out[i] = o;
    }
}

// =====================================================================
// w [K=1024][N] f32 -> wt [N][1024] bf16 (transposed)
// =====================================================================
__global__ __launch_bounds__(256)
void transpose_conv_kernel(const float* __restrict__ w, ushort_t* __restrict__ wt, int N)
{
    __shared__ float t[64][65];
    const int tid = threadIdx.x;
    const int k0 = blockIdx.y * 64, n0 = blockIdx.x * 64;
    #pragma unroll
    for (int rep = 0; rep < 4; ++rep) {
        const int idx = rep * 256 + tid;
        const int r = idx >> 4, c = idx & 15;
        float4 v = *(const float4*)&w[(size_t)(k0 + r) * N + n0 + c * 4];
        t[r][c*4+0] = v.x; t[r][c*4+1] = v.y; t[r][c*4+2] = v.z; t[r][c*4+3] = v.w;
    }
    __syncthreads();
    #pragma unroll
    for (int rep = 0; rep < 4; ++rep) {
        const int idx = rep * 256 + tid;
        const int nl = idx >> 4, kg = idx & 15;
        ushort4_t o;
        o[0] = f2bf(t[kg*4+0][nl]); o[1] = f2bf(t[kg*4+1][nl]);
        o[2] = f2bf(t[kg*4+2][nl]); o[3] = f2bf(t[kg*4+3][nl]);
        *(ushort4_t*)&wt[(size_t)(n0 + nl) * 1024 + k0 + kg*4] = o;
    }
}

// =====================================================================
// bf16 MFMA GEMM (m97 structure).
// MODE 0 scales q by 1/sqrt(64) * log2(e)  (exp2-domain softmax).
// =====================================================================
template<int MODE>
__global__ __launch_bounds__(256)
void gemm_bf16_kernel(const ushort_t* __restrict__ A,
                      const ushort_t* __restrict__ Bt,
                      const float*  __restrict__ bias,
                      ushort_t* __restrict__ out_qb,
                      float*  __restrict__ out_present,
                      float*  __restrict__ out_plain)
{
    __shared__ __attribute__((aligned(16))) ushort_t As[128*32];
    __shared__ __attribute__((aligned(16))) ushort_t Bs[128*32];

    const int tid  = threadIdx.x;
    const int w    = tid >> 6;
    const int lane = tid & 63;
    const int g    = lane >> 4;
    const int ln   = lane & 15;
    const int wr   = w >> 1, wc = w & 1;
    const int row0 = blockIdx.y * 128;
    const int col0 = blockIdx.x * 128;

    int srow[2], sgl[2];
    #pragma unroll
    for (int r = 0; r < 2; ++r) {
        const int o = (w*2 + r) * 1024 + lane * 16;
        srow[r] = o >> 6;
        const int gp = (o >> 4) & 3;
        sgl[r] = gp ^ ((srow[r] >> 1) & 3);
    }

    f32x4 acc[4][4];
    #pragma unroll
    for (int i = 0; i < 4; ++i)
        #pragma unroll
        for (int j = 0; j < 4; ++j)
            acc[i][j] = (f32x4){0.f, 0.f, 0.f, 0.f};

    for (int k0 = 0; k0 < 1024; k0 += 32) {
        #pragma unroll
        for (int r = 0; r < 2; ++r) {
            const int lb = (w*2 + r) * 512;
            gload16(&A [(size_t)(row0 + srow[r]) * 1024 + k0 + sgl[r]*8], &As[lb]);
            gload16(&Bt[(size_t)(col0 + srow[r]) * 1024 + k0 + sgl[r]*8], &Bs[lb]);
        }
        __syncthreads();

        bf16x8 af[4], bfr[4];
        #pragma unroll
        for (int i = 0; i < 4; ++i) {
            const int ra = wr*64 + i*16 + ln;
            const int ga = g ^ ((ra >> 1) & 3);
            af[i] = __builtin_bit_cast(bf16x8, *(const short8_t*)&As[ra*32 + ga*8]);
            const int rb = wc*64 + i*16 + ln;
            const int gb = g ^ ((rb >> 1) & 3);
            bfr[i] = __builtin_bit_cast(bf16x8, *(const short8_t*)&Bs[rb*32 + gb*8]);
        }
        #pragma unroll
        for (int i = 0; i < 4; ++i)
            #pragma unroll
            for (int j = 0; j < 4; ++j)
                acc[i][j] = __builtin_amdgcn_mfma_f32_16x16x32_bf16(af[i], bfr[j], acc[i][j], 0, 0, 0);
        __syncthreads();
    }

    #pragma unroll
    for (int i = 0; i < 4; ++i) {
        #pragma unroll
        for (int j = 0; j < 4; ++j) {
            const int rm = row0 + wr*64 + i*16 + g*4 + j;
            const int b  = rm >> 11;
            const int s  = rm & 2047;
            #pragma unroll
            for (int jn = 0; jn < 4; ++jn) {
                const int e = col0 + wc*64 + jn*16 + ln;
                const float v = acc[i][jn][j] + bias[e];
                if (MODE == 0) {
                    const int which = e >> 10;
                    const int f = e & 1023;
                    const int h = f >> 6, d = f & 63;
                    if (which == 0) {
                        // fold 1/sqrt(depth) * log2(e) into q (exp2 softmax)
                        out_qb[(size_t)(((b*16 + h) * 2048 + s) << 6) + d] =
                            f2bf(v * 0.18033688f);
                    } else {
                        const int kv = which - 1;
                        out_present[((((size_t)(b*2 + kv)*16 + h) * 4096 + 2048 + s) << 6) + d] = v;
                    }
                } else {
                    out_plain[(size_t)rm * 1024 + e] = v;
                }
            }
        }
    }
}

// =====================================================================
// Fused: past -> present (old rows, f32) + present -> K_ws/V_ws bf16.
// kt<32: source = past (also writes present); kt>=32: source = present
// (new rows written by gemm0). One block = one (bh, 64-key tile).
// =====================================================================
__global__ __launch_bounds__(256)
void prep_kv_kernel(const float* __restrict__ past,
                    float* __restrict__ present,
                    ushort_t* __restrict__ Kws, ushort_t* __restrict__ Vws)
{
    __shared__ float tv[64][65];
    const int tid = threadIdx.x;
    const int kt  = blockIdx.x;       // 0..63
    const int bh  = blockIdx.y;       // 0..31
    const int b   = bh >> 4, h = bh & 15;
    const bool old = (kt < 32);

    const float* Kp = old ? past    + (((size_t)(b*2+0)*16 + h) * P_ + kt*64) * 64
                          : present + (((size_t)(b*2+0)*16 + h) * T_ + kt*64) * 64;
    const float* Vp = old ? past    + (((size_t)(b*2+1)*16 + h) * P_ + kt*64) * 64
                          : present + (((size_t)(b*2+1)*16 + h) * T_ + kt*64) * 64;
    float4* PKo = (float4*)(present + (((size_t)(b*2+0)*16 + h) * T_ + kt*64) * 64);
    float4* PVo = (float4*)(present + (((size_t)(b*2+1)*16 + h) * T_ + kt*64) * 64);
    ushort_t* Kd = Kws + ((size_t)bh * T_ + kt*64) * 64;

    #pragma unroll
    for (int rep = 0; rep < 4; ++rep) {
        const int idx = rep * 256 + tid;          // 0..1023 float4s
        float4 v = ((const float4*)Kp)[idx];
        if (old) PKo[idx] = v;
        ushort4_t o;
        o[0] = f2bf(v.x); o[1] = f2bf(v.y); o[2] = f2bf(v.z); o[3] = f2bf(v.w);
        *(ushort4_t*)&Kd[idx*4] = o;
        float4 vv = ((const float4*)Vp)[idx];
        if (old) PVo[idx] = vv;
        const int r = idx >> 4, c = idx & 15;
        tv[r][c*4+0] = vv.x; tv[r][c*4+1] = vv.y;
        tv[r][c*4+2] = vv.z; tv[r][c*4+3] = vv.w;
    }
    __syncthreads();
    #pragma unroll
    for (int rep = 0; rep < 4; ++rep) {
        const int idx = rep * 256 + tid;
        const int d = idx >> 4, pg = idx & 15;
        ushort4_t o;
        o[0] = f2bf(tv[pg*4+0][d]); o[1] = f2bf(tv[pg*4+1][d]);
        o[2] = f2bf(tv[pg*4+2][d]); o[3] = f2bf(tv[pg*4+3][d]);
        *(ushort4_t*)&Vws[((size_t)bh*64 + d) * T_ + kt*64 + pg*4] = o;
    }
}

// =====================================================================
// Flash attention v5: swapped-operand MFMA, in-register exp2 softmax.
// CU-level length balance: same-CU blocks {bid, bid+256, bid+512,
// bid+768} get qblk {a, 15-a, 16+a, 31-a} (a = bid&7) -> every CU's 4
// resident blocks sum to exactly 194 tiles. LDS 40960 B = 4 blocks/CU.
// =====================================================================
__global__ __launch_bounds__(256)
void attn_v5_kernel(const ushort_t* __restrict__ qin,   // [B,H,S,64] bf16 (pre-scaled, log2 domain)
                    const ushort_t* __restrict__ Kws,   // [bh][T][64] bf16
                    const ushort_t* __restrict__ Vws,   // [bh][64][T] bf16
                    ushort_t* __restrict__ merged)      // [B,S,D] bf16
{
    __shared__ __attribute__((aligned(16))) ushort_t Kb[2][4096];   // [64][64]
    __shared__ __attribute__((aligned(16))) ushort_t Vb[2][4096];   // V^T [64 d][64 key]
    __shared__ __attribute__((aligned(16))) ushort_t Pb[4][16][64]; // per-wave P^T, swizzled

    const int tid  = threadIdx.x;
    const int w    = tid >> 6;
    const int lane = tid & 63;
    const int g    = lane >> 4;
    const int ln   = lane & 15;
    const int lnm  = ln & 7;
    const int lsub = lane >> 3;
    const int swz8 = ((lane & 7) ^ lsub) * 8;   // staging source granule swizzle

    // CU-balanced mapping: a = XCD slot, m = CU within XCD, j = resident slot
    const int bid = (int)blockIdx.x;
    const int a   = bid & 7;
    const int m_c = (bid >> 3) & 31;
    const int j   = bid >> 8;
    const int bh  = m_c;
    const int qblk = (j == 0) ? a : (j == 1) ? (15 - a) : (j == 2) ? (16 + a) : (31 - a);
    const int q0   = qblk * 64;
    const int b    = bh >> 4, h = bh & 15;

    const ushort_t* Kbase = Kws + (size_t)bh * T_ * 64;
    const ushort_t* Vbase = Vws + (size_t)bh * 64 * T_;
    const int nt = 33 + qblk;

    // prologue: stage tile 0 into buf 0
    #pragma unroll
    for (int rep = 0; rep < 2; ++rep) {
        const int i = w*2 + rep;
        gload16(Kbase + (((size_t)i*8 + lsub) << 6) + swz8, &Kb[0][i*512]);
        gload16(Vbase + (size_t)(i*8 + lsub) * T_ + swz8,   &Vb[0][i*512]);
    }

    // Q B-frags: col q = ln, k = d = kh*32 + g*8 + e
    bf16x8 qf[2];
    {
        const ushort_t* Qr = qin + ((size_t)bh * S_ + q0 + w*16 + ln) * 64;
        #pragma unroll
        for (int kh = 0; kh < 2; ++kh)
            qf[kh] = __builtin_bit_cast(bf16x8, *(const short8_t*)(Qr + kh*32 + g*8));
    }

    f32x4 o[4];      // O^T: o[dsub][r] = O[d=dsub*16+g*4+r][q=ln]
    #pragma unroll
    for (int d = 0; d < 4; ++d) o[d] = (f32x4){0.f, 0.f, 0.f, 0.f};
    float m = -3.0e38f, l = 0.f;

    int buf = 0;
    for (int t = 0; t < nt; ++t) {
        asm volatile("s_waitcnt vmcnt(0)" ::: "memory");
        __builtin_amdgcn_s_barrier();
        __builtin_amdgcn_sched_barrier(0);

        if (t + 1 < nt) {
            const int t0n = (t + 1) * 64;
            #pragma unroll
            for (int rep = 0; rep < 2; ++rep) {
                const int i = w*2 + rep;
                gload16(Kbase + (((size_t)t0n + i*8 + lsub) << 6) + swz8, &Kb[buf^1][i*512]);
                gload16(Vbase + (size_t)(i*8 + lsub) * T_ + t0n + swz8,   &Vb[buf^1][i*512]);
            }
            __builtin_amdgcn_sched_barrier(0);
        }

        // ---- QK^T swapped: st[js][r] = S[key=js*16+g*4+r][q=ln] (log2 units) ----
        f32x4 st[4];
        __builtin_amdgcn_s_setprio(1);
        #pragma unroll
        for (int js = 0; js < 4; ++js) {
            const ushort_t* kr = &Kb[buf][(js*16 + ln) * 64];
            bf16x8 a0 = __builtin_bit_cast(bf16x8, *(const short8_t*)(kr + ((    g) ^ lnm)*8));
            bf16x8 a1 = __builtin_bit_cast(bf16x8, *(const short8_t*)(kr + ((4 + g) ^ lnm)*8));
            f32x4 z = (f32x4){0.f, 0.f, 0.f, 0.f};
            z = __builtin_amdgcn_mfma_f32_16x16x32_bf16(a0, qf[0], z, 0, 0, 0);
            z = __builtin_amdgcn_mfma_f32_16x16x32_bf16(a1, qf[1], z, 0, 0, 0);
            st[js] = z;
        }
        __builtin_amdgcn_s_setprio(0);

        // ---- causal mask (diagonal tile only) ----
        if (t == nt - 1) {
            const int qr = w*16 + ln;
            #pragma unroll
            for (int js = 0; js < 4; ++js)
                #pragma unroll
                for (int r = 0; r < 4; ++r)
                    if (js*16 + g*4 + r > qr) st[js][r] = -1e30f;
        }

        // ---- in-lane row max + 2 shfls ----
        float mj[4];
        #pragma unroll
        for (int js = 0; js < 4; ++js)
            mj[js] = fmaxf(fmaxf(st[js][0], st[js][1]), fmaxf(st[js][2], st[js][3]));
        float mx = fmaxf(fmaxf(mj[0], mj[1]), fmaxf(mj[2], mj[3]));
        mx = fmaxf(mx, __shfl_xor(mx, 16));
        mx = fmaxf(mx, __shfl_xor(mx, 32));

        // ---- defer-max (T13), log2 domain ----
        if (!__all(mx <= m + 8.0f)) {
            const float mnew = fmaxf(m, mx);
            const float corr = exp2f(m - mnew);
            m = mnew;
            l *= corr;
            #pragma unroll
            for (int d = 0; d < 4; ++d)
                #pragma unroll
                for (int r = 0; r < 4; ++r)
                    o[d][r] *= corr;
        }

        // ---- exp2, sum, packed cvt -> swizzled Pb ----
        float rs = 0.f;
        #pragma unroll
        for (int js = 0; js < 4; ++js) {
            float p0 = exp2f(st[js][0] - m);
            float p1 = exp2f(st[js][1] - m);
            float p2 = exp2f(st[js][2] - m);
            float p3 = exp2f(st[js][3] - m);
            rs += (p0 + p1) + (p2 + p3);
            uint2 pk;
            pk.x = cvt_pk_bf16(p0, p1);
            pk.y = cvt_pk_bf16(p2, p3);
            // 8B granule (js*4+g), XOR-swizzled by (lnm<<1) (even -> keeps pairs)
            *(uint2*)&Pb[w][ln][(((js*4 + g) ^ (lnm << 1)) << 2)] = pk;
        }
        rs += __shfl_xor(rs, 16);
        rs += __shfl_xor(rs, 32);
        l += rs;

        // ---- PV swapped: o[dsub] += mfma(V^T-frag, P^T-frag) ----
        __builtin_amdgcn_s_setprio(1);
        #pragma unroll
        for (int kh = 0; kh < 2; ++kh) {
            bf16x8 pfr = __builtin_bit_cast(bf16x8,
                           *(const short8_t*)&Pb[w][ln][(((kh*4 + g) ^ lnm) << 3)]);
            #pragma unroll
            for (int dsub = 0; dsub < 4; ++dsub) {
                const ushort_t* vr = &Vb[buf][(dsub*16 + ln) * 64];
                bf16x8 va = __builtin_bit_cast(bf16x8,
                              *(const short8_t*)(vr + ((kh*4 + g) ^ lnm)*8));
                o[dsub] = __builtin_amdgcn_mfma_f32_16x16x32_bf16(va, pfr, o[dsub], 0, 0, 0);
            }
        }
        __builtin_amdgcn_s_setprio(0);

        buf ^= 1;
    }

    // ---- epilogue: O[d][q=ln] / l -> merged[b, q, h*64+d] ----
    const float inv = 1.f / l;
    const int row = q0 + w*16 + ln;
    #pragma unroll
    for (int dsub = 0; dsub < 4; ++dsub) {
        ushort4_t ov;
        ov[0] = f2bf(o[dsub][0] * inv);
        ov[1] = f2bf(o[dsub][1] * inv);
        ov[2] = f2bf(o[dsub][2] * inv);
        ov[3] = f2bf(o[dsub][3] * inv);
        *(ushort4_t*)&merged[((size_t)b * S_ + row) * D_ + h*64 + dsub*16 + g*4] = ov;
    }
}

// =====================================================================
extern "C" void kernel_launch(void* const* d_in, const int* in_sizes, int n_in,
                              void* d_out, int out_size, void* d_ws, size_t ws_size,
                              hipStream_t stream)
{
    const float* x      = (const float*)d_in[0];
    // d_in[1] = mask: causal structure computed analytically, never read
    const float* past   = (const float*)d_in[2];
    const float* w_attn = (const float*)d_in[3];
    const float* b_attn = (const float*)d_in[4];
    const float* w_proj = (const float*)d_in[5];
    const float* b_proj = (const float*)d_in[6];

    float* out     = (float*)d_out;                    // [B,S,D]
    float* present = out + (size_t)B_ * S_ * D_;       // [B,2,H,T,64]

    // ws layout (ushorts)
    ushort_t* wsu     = (ushort_t*)d_ws;
    ushort_t* q_ws    = wsu;                  // [B,H,S,64]   8 MB
    ushort_t* mergedb = wsu + 4194304;        // [4096][1024] 8 MB
    ushort_t* wptb    = wsu + 8388608;        // [1024][1024] 2 MB
    ushort_t* xb      = wsu + 9437184;        // [4096][1024] 8 MB (dead after gemm0)
    ushort_t* watb    = wsu + 13631488;       // [3072][1024] 6 MB (dead after gemm0)
    ushort_t* K_ws    = wsu + 9437184;        // overlays xb/watb: [32][T][64] 16 MB
    ushort_t* V_ws    = wsu + 17825792;       // [32][64][T] 16 MB

    // 0) prep
    convert_bf16_kernel<<<2048, 256, 0, stream>>>(
        (const float4*)x, (ushort4_t*)xb, (B_*S_*D_)/4);
    transpose_conv_kernel<<<dim3(48, 16), 256, 0, stream>>>(w_attn, watb, 3072);
    transpose_conv_kernel<<<dim3(16, 16), 256, 0, stream>>>(w_proj, wptb, 1024);

    // 1) QKV projection; q (exp2-domain pre-scaled) -> bf16 ws, k/v -> present f32
    gemm_bf16_kernel<0><<<dim3(24, 32), 256, 0, stream>>>(
        xb, watb, b_attn, q_ws, present, nullptr);

    // 2) fused: past->present (old rows) + present -> bf16 K_ws + V_ws^T
    prep_kv_kernel<<<dim3(64, 32), 256, 0, stream>>>(past, present, K_ws, V_ws);

    // 3) flash attention v5 -> merged bf16
    attn_v5_kernel<<<dim3(1024), 256, 0, stream>>>(q_ws, K_ws, V_ws, mergedb);

    // 4) output projection
    gemm_bf16_kernel<1><<<dim3(8, 32), 256, 0, stream>>>(
        mergedb, wptb, b_proj, nullptr, nullptr, out);
}

// Round 9
// 216.990 us; speedup vs baseline: 1.0673x; 1.0673x over previous
//
#include <hip/hip_runtime.h>
#include <hip/hip_bf16.h>

// Problem constants
#define B_ 2
#define S_ 2048
#define D_ 1024
#define H_ 16
#define P_ 2048
#define T_ 4096   // P_ + S_
#define DEPTH_ 64

typedef __bf16 bf16x8 __attribute__((ext_vector_type(8)));
typedef float  f32x4  __attribute__((ext_vector_type(4)));
typedef short  short8_t __attribute__((ext_vector_type(8)));
typedef unsigned short ushort_t;
typedef unsigned short ushort4_t __attribute__((ext_vector_type(4)));

// f32 -> bf16 round-to-nearest-even (cold paths)
__device__ __forceinline__ ushort_t f2bf(float f) {
    union { float f; unsigned u; } v; v.f = f;
    return (ushort_t)((v.u + 0x7fffu + ((v.u >> 16) & 1u)) >> 16);
}

// packed pair f32 -> 2x bf16 in one u32 (hot path; no builtin on gfx950)
__device__ __forceinline__ unsigned cvt_pk_bf16(float lo, float hi) {
    unsigned r;
    asm("v_cvt_pk_bf16_f32 %0, %1, %2" : "=v"(r) : "v"(lo), "v"(hi));
    return r;
}

__device__ __forceinline__ void gload16(const void* g, void* l) {
    __builtin_amdgcn_global_load_lds(
        (const __attribute__((address_space(1))) unsigned int*)g,
        (__attribute__((address_space(3))) unsigned int*)l, 16, 0, 0);
}

// =====================================================================
// x [4096][1024] f32 -> bf16
// =====================================================================
__global__ __launch_bounds__(256)
void convert_bf16_kernel(const float4* __restrict__ in, ushort4_t* __restrict__ out, int n4)
{
    for (int i = blockIdx.x * 256 + threadIdx.x; i < n4; i += gridDim.x * 256) {
        float4 v = in[i];
        ushort4_t o;
        o[0] = f2bf(v.x); o[1] = f2bf(v.y); o[2] = f2bf(v.z); o[3] = f2bf(v.w);
        out[i] = o;
    }
}

// =====================================================================
// w [K=1024][N] f32 -> wt [N][1024] bf16 (transposed)
// =====================================================================
__global__ __launch_bounds__(256)
void transpose_conv_kernel(const float* __restrict__ w, ushort_t* __restrict__ wt, int N)
{
    __shared__ float t[64][65];
    const int tid = threadIdx.x;
    const int k0 = blockIdx.y * 64, n0 = blockIdx.x * 64;
    #pragma unroll
    for (int rep = 0; rep < 4; ++rep) {
        const int idx = rep * 256 + tid;
        const int r = idx >> 4, c = idx & 15;
        float4 v = *(const float4*)&w[(size_t)(k0 + r) * N + n0 + c * 4];
        t[r][c*4+0] = v.x; t[r][c*4+1] = v.y; t[r][c*4+2] = v.z; t[r][c*4+3] = v.w;
    }
    __syncthreads();
    #pragma unroll
    for (int rep = 0; rep < 4; ++rep) {
        const int idx = rep * 256 + tid;
        const int nl = idx >> 4, kg = idx & 15;
        ushort4_t o;
        o[0] = f2bf(t[kg*4+0][nl]); o[1] = f2bf(t[kg*4+1][nl]);
        o[2] = f2bf(t[kg*4+2][nl]); o[3] = f2bf(t[kg*4+3][nl]);
        *(ushort4_t*)&wt[(size_t)(n0 + nl) * 1024 + k0 + kg*4] = o;
    }
}

// =====================================================================
// bf16 MFMA GEMM (m97 structure).
// MODE 0 scales q by 1/sqrt(64) * log2(e)  (exp2-domain softmax).
// =====================================================================
template<int MODE>
__global__ __launch_bounds__(256)
void gemm_bf16_kernel(const ushort_t* __restrict__ A,
                      const ushort_t* __restrict__ Bt,
                      const float*  __restrict__ bias,
                      ushort_t* __restrict__ out_qb,
                      float*  __restrict__ out_present,
                      float*  __restrict__ out_plain)
{
    __shared__ __attribute__((aligned(16))) ushort_t As[128*32];
    __shared__ __attribute__((aligned(16))) ushort_t Bs[128*32];

    const int tid  = threadIdx.x;
    const int w    = tid >> 6;
    const int lane = tid & 63;
    const int g    = lane >> 4;
    const int ln   = lane & 15;
    const int wr   = w >> 1, wc = w & 1;
    const int row0 = blockIdx.y * 128;
    const int col0 = blockIdx.x * 128;

    int srow[2], sgl[2];
    #pragma unroll
    for (int r = 0; r < 2; ++r) {
        const int o = (w*2 + r) * 1024 + lane * 16;
        srow[r] = o >> 6;
        const int gp = (o >> 4) & 3;
        sgl[r] = gp ^ ((srow[r] >> 1) & 3);
    }

    f32x4 acc[4][4];
    #pragma unroll
    for (int i = 0; i < 4; ++i)
        #pragma unroll
        for (int j = 0; j < 4; ++j)
            acc[i][j] = (f32x4){0.f, 0.f, 0.f, 0.f};

    for (int k0 = 0; k0 < 1024; k0 += 32) {
        #pragma unroll
        for (int r = 0; r < 2; ++r) {
            const int lb = (w*2 + r) * 512;
            gload16(&A [(size_t)(row0 + srow[r]) * 1024 + k0 + sgl[r]*8], &As[lb]);
            gload16(&Bt[(size_t)(col0 + srow[r]) * 1024 + k0 + sgl[r]*8], &Bs[lb]);
        }
        __syncthreads();

        bf16x8 af[4], bfr[4];
        #pragma unroll
        for (int i = 0; i < 4; ++i) {
            const int ra = wr*64 + i*16 + ln;
            const int ga = g ^ ((ra >> 1) & 3);
            af[i] = __builtin_bit_cast(bf16x8, *(const short8_t*)&As[ra*32 + ga*8]);
            const int rb = wc*64 + i*16 + ln;
            const int gb = g ^ ((rb >> 1) & 3);
            bfr[i] = __builtin_bit_cast(bf16x8, *(const short8_t*)&Bs[rb*32 + gb*8]);
        }
        #pragma unroll
        for (int i = 0; i < 4; ++i)
            #pragma unroll
            for (int j = 0; j < 4; ++j)
                acc[i][j] = __builtin_amdgcn_mfma_f32_16x16x32_bf16(af[i], bfr[j], acc[i][j], 0, 0, 0);
        __syncthreads();
    }

    #pragma unroll
    for (int i = 0; i < 4; ++i) {
        #pragma unroll
        for (int j = 0; j < 4; ++j) {
            const int rm = row0 + wr*64 + i*16 + g*4 + j;
            const int b  = rm >> 11;
            const int s  = rm & 2047;
            #pragma unroll
            for (int jn = 0; jn < 4; ++jn) {
                const int e = col0 + wc*64 + jn*16 + ln;
                const float v = acc[i][jn][j] + bias[e];
                if (MODE == 0) {
                    const int which = e >> 10;
                    const int f = e & 1023;
                    const int h = f >> 6, d = f & 63;
                    if (which == 0) {
                        // fold 1/sqrt(depth) * log2(e) into q (exp2 softmax)
                        out_qb[(size_t)(((b*16 + h) * 2048 + s) << 6) + d] =
                            f2bf(v * 0.18033688f);
                    } else {
                        const int kv = which - 1;
                        out_present[((((size_t)(b*2 + kv)*16 + h) * 4096 + 2048 + s) << 6) + d] = v;
                    }
                } else {
                    out_plain[(size_t)rm * 1024 + e] = v;
                }
            }
        }
    }
}

// =====================================================================
// Fused: past -> present (old rows, f32) + present -> K_ws/V_ws bf16.
// =====================================================================
__global__ __launch_bounds__(256)
void prep_kv_kernel(const float* __restrict__ past,
                    float* __restrict__ present,
                    ushort_t* __restrict__ Kws, ushort_t* __restrict__ Vws)
{
    __shared__ float tv[64][65];
    const int tid = threadIdx.x;
    const int kt  = blockIdx.x;       // 0..63
    const int bh  = blockIdx.y;       // 0..31
    const int b   = bh >> 4, h = bh & 15;
    const bool old = (kt < 32);

    const float* Kp = old ? past    + (((size_t)(b*2+0)*16 + h) * P_ + kt*64) * 64
                          : present + (((size_t)(b*2+0)*16 + h) * T_ + kt*64) * 64;
    const float* Vp = old ? past    + (((size_t)(b*2+1)*16 + h) * P_ + kt*64) * 64
                          : present + (((size_t)(b*2+1)*16 + h) * T_ + kt*64) * 64;
    float4* PKo = (float4*)(present + (((size_t)(b*2+0)*16 + h) * T_ + kt*64) * 64);
    float4* PVo = (float4*)(present + (((size_t)(b*2+1)*16 + h) * T_ + kt*64) * 64);
    ushort_t* Kd = Kws + ((size_t)bh * T_ + kt*64) * 64;

    #pragma unroll
    for (int rep = 0; rep < 4; ++rep) {
        const int idx = rep * 256 + tid;          // 0..1023 float4s
        float4 v = ((const float4*)Kp)[idx];
        if (old) PKo[idx] = v;
        ushort4_t o;
        o[0] = f2bf(v.x); o[1] = f2bf(v.y); o[2] = f2bf(v.z); o[3] = f2bf(v.w);
        *(ushort4_t*)&Kd[idx*4] = o;
        float4 vv = ((const float4*)Vp)[idx];
        if (old) PVo[idx] = vv;
        const int r = idx >> 4, c = idx & 15;
        tv[r][c*4+0] = vv.x; tv[r][c*4+1] = vv.y;
        tv[r][c*4+2] = vv.z; tv[r][c*4+3] = vv.w;
    }
    __syncthreads();
    #pragma unroll
    for (int rep = 0; rep < 4; ++rep) {
        const int idx = rep * 256 + tid;
        const int d = idx >> 4, pg = idx & 15;
        ushort4_t o;
        o[0] = f2bf(tv[pg*4+0][d]); o[1] = f2bf(tv[pg*4+1][d]);
        o[2] = f2bf(tv[pg*4+2][d]); o[3] = f2bf(tv[pg*4+3][d]);
        *(ushort4_t*)&Vws[((size_t)bh*64 + d) * T_ + kt*64 + pg*4] = o;
    }
}

// =====================================================================
// Flash attention v6: swapped-operand MFMA, in-register exp2 softmax.
// Block mapping combines:
//   - XCD locality (round 7): XCD a (= bid&7) handles only bh in
//     {4a..4a+3} -> 4 MB K/V working set per XCD L2 (FETCH ~20 MB).
//   - CU length balance (round 8): same-CU resident slots j=0..3 get
//     qblk {c, 15-c, 16+c, 31-c} -> every CU sums to 194 tiles.
// bid = a + 8m + 256j; bh = a*4 + (m&3); c = m>>2.
// LDS 40960 B = 4 blocks/CU.
// =====================================================================
__global__ __launch_bounds__(256)
void attn_v6_kernel(const ushort_t* __restrict__ qin,   // [B,H,S,64] bf16 (pre-scaled, log2 domain)
                    const ushort_t* __restrict__ Kws,   // [bh][T][64] bf16
                    const ushort_t* __restrict__ Vws,   // [bh][64][T] bf16
                    ushort_t* __restrict__ merged)      // [B,S,D] bf16
{
    __shared__ __attribute__((aligned(16))) ushort_t Kb[2][4096];   // [64][64]
    __shared__ __attribute__((aligned(16))) ushort_t Vb[2][4096];   // V^T [64 d][64 key]
    __shared__ __attribute__((aligned(16))) ushort_t Pb[4][16][64]; // per-wave P^T, swizzled

    const int tid  = threadIdx.x;
    const int w    = tid >> 6;
    const int lane = tid & 63;
    const int g    = lane >> 4;
    const int ln   = lane & 15;
    const int lnm  = ln & 7;
    const int lsub = lane >> 3;
    const int swz8 = ((lane & 7) ^ lsub) * 8;   // staging source granule swizzle

    // XCD-local + CU-balanced mapping
    const int bid = (int)blockIdx.x;
    const int a   = bid & 7;            // XCD slot
    const int m_c = (bid >> 3) & 31;    // CU within XCD
    const int j   = bid >> 8;           // resident slot on that CU
    const int bh  = a * 4 + (m_c & 3);
    const int c   = m_c >> 2;
    const int qblk = (j == 0) ? c : (j == 1) ? (15 - c) : (j == 2) ? (16 + c) : (31 - c);
    const int q0   = qblk * 64;
    const int b    = bh >> 4, h = bh & 15;

    const ushort_t* Kbase = Kws + (size_t)bh * T_ * 64;
    const ushort_t* Vbase = Vws + (size_t)bh * 64 * T_;
    const int nt = 33 + qblk;

    // prologue: stage tile 0 into buf 0
    #pragma unroll
    for (int rep = 0; rep < 2; ++rep) {
        const int i = w*2 + rep;
        gload16(Kbase + (((size_t)i*8 + lsub) << 6) + swz8, &Kb[0][i*512]);
        gload16(Vbase + (size_t)(i*8 + lsub) * T_ + swz8,   &Vb[0][i*512]);
    }

    // Q B-frags: col q = ln, k = d = kh*32 + g*8 + e
    bf16x8 qf[2];
    {
        const ushort_t* Qr = qin + ((size_t)bh * S_ + q0 + w*16 + ln) * 64;
        #pragma unroll
        for (int kh = 0; kh < 2; ++kh)
            qf[kh] = __builtin_bit_cast(bf16x8, *(const short8_t*)(Qr + kh*32 + g*8));
    }

    f32x4 o[4];      // O^T: o[dsub][r] = O[d=dsub*16+g*4+r][q=ln]
    #pragma unroll
    for (int d = 0; d < 4; ++d) o[d] = (f32x4){0.f, 0.f, 0.f, 0.f};
    float m = -3.0e38f, l = 0.f;

    int buf = 0;
    for (int t = 0; t < nt; ++t) {
        asm volatile("s_waitcnt vmcnt(0)" ::: "memory");
        __builtin_amdgcn_s_barrier();
        __builtin_amdgcn_sched_barrier(0);

        if (t + 1 < nt) {
            const int t0n = (t + 1) * 64;
            #pragma unroll
            for (int rep = 0; rep < 2; ++rep) {
                const int i = w*2 + rep;
                gload16(Kbase + (((size_t)t0n + i*8 + lsub) << 6) + swz8, &Kb[buf^1][i*512]);
                gload16(Vbase + (size_t)(i*8 + lsub) * T_ + t0n + swz8,   &Vb[buf^1][i*512]);
            }
            __builtin_amdgcn_sched_barrier(0);
        }

        // ---- QK^T swapped: st[js][r] = S[key=js*16+g*4+r][q=ln] (log2 units) ----
        f32x4 st[4];
        __builtin_amdgcn_s_setprio(1);
        #pragma unroll
        for (int js = 0; js < 4; ++js) {
            const ushort_t* kr = &Kb[buf][(js*16 + ln) * 64];
            bf16x8 a0 = __builtin_bit_cast(bf16x8, *(const short8_t*)(kr + ((    g) ^ lnm)*8));
            bf16x8 a1 = __builtin_bit_cast(bf16x8, *(const short8_t*)(kr + ((4 + g) ^ lnm)*8));
            f32x4 z = (f32x4){0.f, 0.f, 0.f, 0.f};
            z = __builtin_amdgcn_mfma_f32_16x16x32_bf16(a0, qf[0], z, 0, 0, 0);
            z = __builtin_amdgcn_mfma_f32_16x16x32_bf16(a1, qf[1], z, 0, 0, 0);
            st[js] = z;
        }
        __builtin_amdgcn_s_setprio(0);

        // ---- causal mask (diagonal tile only) ----
        if (t == nt - 1) {
            const int qr = w*16 + ln;
            #pragma unroll
            for (int js = 0; js < 4; ++js)
                #pragma unroll
                for (int r = 0; r < 4; ++r)
                    if (js*16 + g*4 + r > qr) st[js][r] = -1e30f;
        }

        // ---- in-lane row max + 2 shfls ----
        float mj[4];
        #pragma unroll
        for (int js = 0; js < 4; ++js)
            mj[js] = fmaxf(fmaxf(st[js][0], st[js][1]), fmaxf(st[js][2], st[js][3]));
        float mx = fmaxf(fmaxf(mj[0], mj[1]), fmaxf(mj[2], mj[3]));
        mx = fmaxf(mx, __shfl_xor(mx, 16));
        mx = fmaxf(mx, __shfl_xor(mx, 32));

        // ---- defer-max (T13), log2 domain ----
        if (!__all(mx <= m + 8.0f)) {
            const float mnew = fmaxf(m, mx);
            const float corr = exp2f(m - mnew);
            m = mnew;
            l *= corr;
            #pragma unroll
            for (int d = 0; d < 4; ++d)
                #pragma unroll
                for (int r = 0; r < 4; ++r)
                    o[d][r] *= corr;
        }

        // ---- exp2, sum, packed cvt -> swizzled Pb ----
        float rs = 0.f;
        #pragma unroll
        for (int js = 0; js < 4; ++js) {
            float p0 = exp2f(st[js][0] - m);
            float p1 = exp2f(st[js][1] - m);
            float p2 = exp2f(st[js][2] - m);
            float p3 = exp2f(st[js][3] - m);
            rs += (p0 + p1) + (p2 + p3);
            uint2 pk;
            pk.x = cvt_pk_bf16(p0, p1);
            pk.y = cvt_pk_bf16(p2, p3);
            // 8B granule (js*4+g), XOR-swizzled by (lnm<<1) (even -> keeps pairs)
            *(uint2*)&Pb[w][ln][(((js*4 + g) ^ (lnm << 1)) << 2)] = pk;
        }
        rs += __shfl_xor(rs, 16);
        rs += __shfl_xor(rs, 32);
        l += rs;

        // ---- PV swapped: o[dsub] += mfma(V^T-frag, P^T-frag) ----
        __builtin_amdgcn_s_setprio(1);
        #pragma unroll
        for (int kh = 0; kh < 2; ++kh) {
            bf16x8 pfr = __builtin_bit_cast(bf16x8,
                           *(const short8_t*)&Pb[w][ln][(((kh*4 + g) ^ lnm) << 3)]);
            #pragma unroll
            for (int dsub = 0; dsub < 4; ++dsub) {
                const ushort_t* vr = &Vb[buf][(dsub*16 + ln) * 64];
                bf16x8 va = __builtin_bit_cast(bf16x8,
                              *(const short8_t*)(vr + ((kh*4 + g) ^ lnm)*8));
                o[dsub] = __builtin_amdgcn_mfma_f32_16x16x32_bf16(va, pfr, o[dsub], 0, 0, 0);
            }
        }
        __builtin_amdgcn_s_setprio(0);

        buf ^= 1;
    }

    // ---- epilogue: O[d][q=ln] / l -> merged[b, q, h*64+d] ----
    const float inv = 1.f / l;
    const int row = q0 + w*16 + ln;
    #pragma unroll
    for (int dsub = 0; dsub < 4; ++dsub) {
        ushort4_t ov;
        ov[0] = f2bf(o[dsub][0] * inv);
        ov[1] = f2bf(o[dsub][1] * inv);
        ov[2] = f2bf(o[dsub][2] * inv);
        ov[3] = f2bf(o[dsub][3] * inv);
        *(ushort4_t*)&merged[((size_t)b * S_ + row) * D_ + h*64 + dsub*16 + g*4] = ov;
    }
}

// =====================================================================
extern "C" void kernel_launch(void* const* d_in, const int* in_sizes, int n_in,
                              void* d_out, int out_size, void* d_ws, size_t ws_size,
                              hipStream_t stream)
{
    const float* x      = (const float*)d_in[0];
    // d_in[1] = mask: causal structure computed analytically, never read
    const float* past   = (const float*)d_in[2];
    const float* w_attn = (const float*)d_in[3];
    const float* b_attn = (const float*)d_in[4];
    const float* w_proj = (const float*)d_in[5];
    const float* b_proj = (const float*)d_in[6];

    float* out     = (float*)d_out;                    // [B,S,D]
    float* present = out + (size_t)B_ * S_ * D_;       // [B,2,H,T,64]

    // ws layout (ushorts)
    ushort_t* wsu     = (ushort_t*)d_ws;
    ushort_t* q_ws    = wsu;                  // [B,H,S,64]   8 MB
    ushort_t* mergedb = wsu + 4194304;        // [4096][1024] 8 MB
    ushort_t* wptb    = wsu + 8388608;        // [1024][1024] 2 MB
    ushort_t* xb      = wsu + 9437184;        // [4096][1024] 8 MB (dead after gemm0)
    ushort_t* watb    = wsu + 13631488;       // [3072][1024] 6 MB (dead after gemm0)
    ushort_t* K_ws    = wsu + 9437184;        // overlays xb/watb: [32][T][64] 16 MB
    ushort_t* V_ws    = wsu + 17825792;       // [32][64][T] 16 MB

    // 0) prep
    convert_bf16_kernel<<<2048, 256, 0, stream>>>(
        (const float4*)x, (ushort4_t*)xb, (B_*S_*D_)/4);
    transpose_conv_kernel<<<dim3(48, 16), 256, 0, stream>>>(w_attn, watb, 3072);
    transpose_conv_kernel<<<dim3(16, 16), 256, 0, stream>>>(w_proj, wptb, 1024);

    // 1) QKV projection; q (exp2-domain pre-scaled) -> bf16 ws, k/v -> present f32
    gemm_bf16_kernel<0><<<dim3(24, 32), 256, 0, stream>>>(
        xb, watb, b_attn, q_ws, present, nullptr);

    // 2) fused: past->present (old rows) + present -> bf16 K_ws + V_ws^T
    prep_kv_kernel<<<dim3(64, 32), 256, 0, stream>>>(past, present, K_ws, V_ws);

    // 3) flash attention v6 -> merged bf16
    attn_v6_kernel<<<dim3(1024), 256, 0, stream>>>(q_ws, K_ws, V_ws, mergedb);

    // 4) output projection
    gemm_bf16_kernel<1><<<dim3(8, 32), 256, 0, stream>>>(
        mergedb, wptb, b_proj, nullptr, nullptr, out);
}

// Round 10
// 209.707 us; speedup vs baseline: 1.1044x; 1.0347x over previous
//
#include <hip/hip_runtime.h>
#include <hip/hip_bf16.h>

// Problem constants
#define B_ 2
#define S_ 2048
#define D_ 1024
#define H_ 16
#define P_ 2048
#define T_ 4096   // P_ + S_
#define DEPTH_ 64

typedef __bf16 bf16x8 __attribute__((ext_vector_type(8)));
typedef float  f32x4  __attribute__((ext_vector_type(4)));
typedef short  short8_t __attribute__((ext_vector_type(8)));
typedef unsigned short ushort_t;
typedef unsigned short ushort4_t __attribute__((ext_vector_type(4)));

// f32 -> bf16 round-to-nearest-even (cold paths)
__device__ __forceinline__ ushort_t f2bf(float f) {
    union { float f; unsigned u; } v; v.f = f;
    return (ushort_t)((v.u + 0x7fffu + ((v.u >> 16) & 1u)) >> 16);
}

// packed pair f32 -> 2x bf16 in one u32 (hot path; no builtin on gfx950)
__device__ __forceinline__ unsigned cvt_pk_bf16(float lo, float hi) {
    unsigned r;
    asm("v_cvt_pk_bf16_f32 %0, %1, %2" : "=v"(r) : "v"(lo), "v"(hi));
    return r;
}

__device__ __forceinline__ void gload16(const void* g, void* l) {
    __builtin_amdgcn_global_load_lds(
        (const __attribute__((address_space(1))) unsigned int*)g,
        (__attribute__((address_space(3))) unsigned int*)l, 16, 0, 0);
}

// =====================================================================
// x [4096][1024] f32 -> bf16
// =====================================================================
__global__ __launch_bounds__(256)
void convert_bf16_kernel(const float4* __restrict__ in, ushort4_t* __restrict__ out, int n4)
{
    for (int i = blockIdx.x * 256 + threadIdx.x; i < n4; i += gridDim.x * 256) {
        float4 v = in[i];
        ushort4_t o;
        o[0] = f2bf(v.x); o[1] = f2bf(v.y); o[2] = f2bf(v.z); o[3] = f2bf(v.w);
        out[i] = o;
    }
}

// =====================================================================
// w [K=1024][N] f32 -> wt [N][1024] bf16 (transposed)
// =====================================================================
__global__ __launch_bounds__(256)
void transpose_conv_kernel(const float* __restrict__ w, ushort_t* __restrict__ wt, int N)
{
    __shared__ float t[64][65];
    const int tid = threadIdx.x;
    const int k0 = blockIdx.y * 64, n0 = blockIdx.x * 64;
    #pragma unroll
    for (int rep = 0; rep < 4; ++rep) {
        const int idx = rep * 256 + tid;
        const int r = idx >> 4, c = idx & 15;
        float4 v = *(const float4*)&w[(size_t)(k0 + r) * N + n0 + c * 4];
        t[r][c*4+0] = v.x; t[r][c*4+1] = v.y; t[r][c*4+2] = v.z; t[r][c*4+3] = v.w;
    }
    __syncthreads();
    #pragma unroll
    for (int rep = 0; rep < 4; ++rep) {
        const int idx = rep * 256 + tid;
        const int nl = idx >> 4, kg = idx & 15;
        ushort4_t o;
        o[0] = f2bf(t[kg*4+0][nl]); o[1] = f2bf(t[kg*4+1][nl]);
        o[2] = f2bf(t[kg*4+2][nl]); o[3] = f2bf(t[kg*4+3][nl]);
        *(ushort4_t*)&wt[(size_t)(n0 + nl) * 1024 + k0 + kg*4] = o;
    }
}

// =====================================================================
// bf16 MFMA GEMM (m97 structure).
// MODE 0 scales q by 1/sqrt(64) * log2(e)  (exp2-domain softmax).
// =====================================================================
template<int MODE>
__global__ __launch_bounds__(256)
void gemm_bf16_kernel(const ushort_t* __restrict__ A,
                      const ushort_t* __restrict__ Bt,
                      const float*  __restrict__ bias,
                      ushort_t* __restrict__ out_qb,
                      float*  __restrict__ out_present,
                      float*  __restrict__ out_plain)
{
    __shared__ __attribute__((aligned(16))) ushort_t As[128*32];
    __shared__ __attribute__((aligned(16))) ushort_t Bs[128*32];

    const int tid  = threadIdx.x;
    const int w    = tid >> 6;
    const int lane = tid & 63;
    const int g    = lane >> 4;
    const int ln   = lane & 15;
    const int wr   = w >> 1, wc = w & 1;
    const int row0 = blockIdx.y * 128;
    const int col0 = blockIdx.x * 128;

    int srow[2], sgl[2];
    #pragma unroll
    for (int r = 0; r < 2; ++r) {
        const int o = (w*2 + r) * 1024 + lane * 16;
        srow[r] = o >> 6;
        const int gp = (o >> 4) & 3;
        sgl[r] = gp ^ ((srow[r] >> 1) & 3);
    }

    f32x4 acc[4][4];
    #pragma unroll
    for (int i = 0; i < 4; ++i)
        #pragma unroll
        for (int j = 0; j < 4; ++j)
            acc[i][j] = (f32x4){0.f, 0.f, 0.f, 0.f};

    for (int k0 = 0; k0 < 1024; k0 += 32) {
        #pragma unroll
        for (int r = 0; r < 2; ++r) {
            const int lb = (w*2 + r) * 512;
            gload16(&A [(size_t)(row0 + srow[r]) * 1024 + k0 + sgl[r]*8], &As[lb]);
            gload16(&Bt[(size_t)(col0 + srow[r]) * 1024 + k0 + sgl[r]*8], &Bs[lb]);
        }
        __syncthreads();

        bf16x8 af[4], bfr[4];
        #pragma unroll
        for (int i = 0; i < 4; ++i) {
            const int ra = wr*64 + i*16 + ln;
            const int ga = g ^ ((ra >> 1) & 3);
            af[i] = __builtin_bit_cast(bf16x8, *(const short8_t*)&As[ra*32 + ga*8]);
            const int rb = wc*64 + i*16 + ln;
            const int gb = g ^ ((rb >> 1) & 3);
            bfr[i] = __builtin_bit_cast(bf16x8, *(const short8_t*)&Bs[rb*32 + gb*8]);
        }
        #pragma unroll
        for (int i = 0; i < 4; ++i)
            #pragma unroll
            for (int j = 0; j < 4; ++j)
                acc[i][j] = __builtin_amdgcn_mfma_f32_16x16x32_bf16(af[i], bfr[j], acc[i][j], 0, 0, 0);
        __syncthreads();
    }

    #pragma unroll
    for (int i = 0; i < 4; ++i) {
        #pragma unroll
        for (int j = 0; j < 4; ++j) {
            const int rm = row0 + wr*64 + i*16 + g*4 + j;
            const int b  = rm >> 11;
            const int s  = rm & 2047;
            #pragma unroll
            for (int jn = 0; jn < 4; ++jn) {
                const int e = col0 + wc*64 + jn*16 + ln;
                const float v = acc[i][jn][j] + bias[e];
                if (MODE == 0) {
                    const int which = e >> 10;
                    const int f = e & 1023;
                    const int h = f >> 6, d = f & 63;
                    if (which == 0) {
                        // fold 1/sqrt(depth) * log2(e) into q (exp2 softmax)
                        out_qb[(size_t)(((b*16 + h) * 2048 + s) << 6) + d] =
                            f2bf(v * 0.18033688f);
                    } else {
                        const int kv = which - 1;
                        out_present[((((size_t)(b*2 + kv)*16 + h) * 4096 + 2048 + s) << 6) + d] = v;
                    }
                } else {
                    out_plain[(size_t)rm * 1024 + e] = v;
                }
            }
        }
    }
}

// =====================================================================
// Fused: past -> present (old rows, f32) + present -> K_ws/V_ws bf16.
// =====================================================================
__global__ __launch_bounds__(256)
void prep_kv_kernel(const float* __restrict__ past,
                    float* __restrict__ present,
                    ushort_t* __restrict__ Kws, ushort_t* __restrict__ Vws)
{
    __shared__ float tv[64][65];
    const int tid = threadIdx.x;
    const int kt  = blockIdx.x;       // 0..63
    const int bh  = blockIdx.y;       // 0..31
    const int b   = bh >> 4, h = bh & 15;
    const bool old = (kt < 32);

    const float* Kp = old ? past    + (((size_t)(b*2+0)*16 + h) * P_ + kt*64) * 64
                          : present + (((size_t)(b*2+0)*16 + h) * T_ + kt*64) * 64;
    const float* Vp = old ? past    + (((size_t)(b*2+1)*16 + h) * P_ + kt*64) * 64
                          : present + (((size_t)(b*2+1)*16 + h) * T_ + kt*64) * 64;
    float4* PKo = (float4*)(present + (((size_t)(b*2+0)*16 + h) * T_ + kt*64) * 64);
    float4* PVo = (float4*)(present + (((size_t)(b*2+1)*16 + h) * T_ + kt*64) * 64);
    ushort_t* Kd = Kws + ((size_t)bh * T_ + kt*64) * 64;

    #pragma unroll
    for (int rep = 0; rep < 4; ++rep) {
        const int idx = rep * 256 + tid;          // 0..1023 float4s
        float4 v = ((const float4*)Kp)[idx];
        if (old) PKo[idx] = v;
        ushort4_t o;
        o[0] = f2bf(v.x); o[1] = f2bf(v.y); o[2] = f2bf(v.z); o[3] = f2bf(v.w);
        *(ushort4_t*)&Kd[idx*4] = o;
        float4 vv = ((const float4*)Vp)[idx];
        if (old) PVo[idx] = vv;
        const int r = idx >> 4, c = idx & 15;
        tv[r][c*4+0] = vv.x; tv[r][c*4+1] = vv.y;
        tv[r][c*4+2] = vv.z; tv[r][c*4+3] = vv.w;
    }
    __syncthreads();
    #pragma unroll
    for (int rep = 0; rep < 4; ++rep) {
        const int idx = rep * 256 + tid;
        const int d = idx >> 4, pg = idx & 15;
        ushort4_t o;
        o[0] = f2bf(tv[pg*4+0][d]); o[1] = f2bf(tv[pg*4+1][d]);
        o[2] = f2bf(tv[pg*4+2][d]); o[3] = f2bf(tv[pg*4+3][d]);
        *(ushort4_t*)&Vws[((size_t)bh*64 + d) * T_ + kt*64 + pg*4] = o;
    }
}

// =====================================================================
// Flash attention v7 = v6 + (a) __launch_bounds__(256,4) so the
// allocator targets the true 4-waves/SIMD occupancy (LDS-capped) and
// keeps addresses resident; (b) KV loop unrolled x2 with COMPILE-TIME
// buffer indices (static LDS bases + immediate offsets, no runtime
// buf math); (c) staging offsets hoisted.
// Mapping unchanged: XCD-local bh, CU-balanced qblk.
// =====================================================================
__global__ __launch_bounds__(256, 4)
void attn_v7_kernel(const ushort_t* __restrict__ qin,   // [B,H,S,64] bf16 (pre-scaled, log2 domain)
                    const ushort_t* __restrict__ Kws,   // [bh][T][64] bf16
                    const ushort_t* __restrict__ Vws,   // [bh][64][T] bf16
                    ushort_t* __restrict__ merged)      // [B,S,D] bf16
{
    __shared__ __attribute__((aligned(16))) ushort_t Kb0[4096];   // K tile buf0 [64][64]
    __shared__ __attribute__((aligned(16))) ushort_t Kb1[4096];   // K tile buf1
    __shared__ __attribute__((aligned(16))) ushort_t Vb0[4096];   // V^T tile buf0 [64 d][64 key]
    __shared__ __attribute__((aligned(16))) ushort_t Vb1[4096];   // V^T tile buf1
    __shared__ __attribute__((aligned(16))) ushort_t Pb[4][16][64]; // per-wave P^T, swizzled

    const int tid  = threadIdx.x;
    const int w    = tid >> 6;
    const int lane = tid & 63;
    const int g    = lane >> 4;
    const int ln   = lane & 15;
    const int lnm  = ln & 7;
    const int lsub = lane >> 3;
    const int swz8 = ((lane & 7) ^ lsub) * 8;   // staging source granule swizzle

    // XCD-local + CU-balanced mapping
    const int bid = (int)blockIdx.x;
    const int a   = bid & 7;            // XCD slot
    const int m_c = (bid >> 3) & 31;    // CU within XCD
    const int j   = bid >> 8;           // resident slot on that CU
    const int bh  = a * 4 + (m_c & 3);
    const int c   = m_c >> 2;
    const int qblk = (j == 0) ? c : (j == 1) ? (15 - c) : (j == 2) ? (16 + c) : (31 - c);
    const int q0   = qblk * 64;
    const int b    = bh >> 4, h = bh & 15;

    const ushort_t* Kbase = Kws + (size_t)bh * T_ * 64;
    const ushort_t* Vbase = Vws + (size_t)bh * 64 * T_;
    const int nt = 33 + qblk;

    // hoisted staging offsets (loop-invariant)
    const int kgOff0 = ((w*16 + 0 + lsub) << 6) + swz8;      // rep 0 row offset
    const int kgOff1 = ((w*16 + 8 + lsub) << 6) + swz8;      // rep 1
    const size_t vgOff0 = (size_t)(w*16 + 0 + lsub) * T_ + swz8;
    const size_t vgOff1 = (size_t)(w*16 + 8 + lsub) * T_ + swz8;
    const int ldsOff0 = (w*2 + 0) * 512;
    const int ldsOff1 = (w*2 + 1) * 512;

    // prologue: stage tile 0 into buf 0
    gload16(Kbase + kgOff0, &Kb0[ldsOff0]);
    gload16(Kbase + kgOff1, &Kb0[ldsOff1]);
    gload16(Vbase + vgOff0, &Vb0[ldsOff0]);
    gload16(Vbase + vgOff1, &Vb0[ldsOff1]);

    // Q B-frags: col q = ln, k = d = kh*32 + g*8 + e
    bf16x8 qf[2];
    {
        const ushort_t* Qr = qin + ((size_t)bh * S_ + q0 + w*16 + ln) * 64;
        #pragma unroll
        for (int kh = 0; kh < 2; ++kh)
            qf[kh] = __builtin_bit_cast(bf16x8, *(const short8_t*)(Qr + kh*32 + g*8));
    }

    f32x4 o[4];      // O^T: o[dsub][r] = O[d=dsub*16+g*4+r][q=ln]
    #pragma unroll
    for (int d = 0; d < 4; ++d) o[d] = (f32x4){0.f, 0.f, 0.f, 0.f};
    float m = -3.0e38f, l = 0.f;

#define ATTN_BODY(KBUF, VBUF, NBUF_K, NBUF_V)                                   \
    {                                                                           \
        asm volatile("s_waitcnt vmcnt(0)" ::: "memory");                        \
        __builtin_amdgcn_s_barrier();                                           \
        __builtin_amdgcn_sched_barrier(0);                                      \
        if (t + 1 < nt) {                                                       \
            const size_t t0n = (size_t)(t + 1) * 64;                            \
            gload16(Kbase + (t0n << 6) + kgOff0, &NBUF_K[ldsOff0]);             \
            gload16(Kbase + (t0n << 6) + kgOff1, &NBUF_K[ldsOff1]);             \
            gload16(Vbase + vgOff0 + t0n, &NBUF_V[ldsOff0]);                    \
            gload16(Vbase + vgOff1 + t0n, &NBUF_V[ldsOff1]);                    \
            __builtin_amdgcn_sched_barrier(0);                                  \
        }                                                                       \
        f32x4 st[4];                                                            \
        __builtin_amdgcn_s_setprio(1);                                          \
        _Pragma("unroll")                                                       \
        for (int js = 0; js < 4; ++js) {                                        \
            const ushort_t* kr = &KBUF[(js*16 + ln) * 64];                      \
            bf16x8 a0 = __builtin_bit_cast(bf16x8, *(const short8_t*)(kr + ((    g) ^ lnm)*8)); \
            bf16x8 a1 = __builtin_bit_cast(bf16x8, *(const short8_t*)(kr + ((4 + g) ^ lnm)*8)); \
            f32x4 z = (f32x4){0.f, 0.f, 0.f, 0.f};                              \
            z = __builtin_amdgcn_mfma_f32_16x16x32_bf16(a0, qf[0], z, 0, 0, 0); \
            z = __builtin_amdgcn_mfma_f32_16x16x32_bf16(a1, qf[1], z, 0, 0, 0); \
            st[js] = z;                                                         \
        }                                                                       \
        __builtin_amdgcn_s_setprio(0);                                          \
        if (t == nt - 1) {                                                      \
            const int qr = w*16 + ln;                                           \
            _Pragma("unroll")                                                   \
            for (int js = 0; js < 4; ++js)                                      \
                _Pragma("unroll")                                               \
                for (int r = 0; r < 4; ++r)                                     \
                    if (js*16 + g*4 + r > qr) st[js][r] = -1e30f;               \
        }                                                                       \
        float mj[4];                                                            \
        _Pragma("unroll")                                                       \
        for (int js = 0; js < 4; ++js)                                          \
            mj[js] = fmaxf(fmaxf(st[js][0], st[js][1]), fmaxf(st[js][2], st[js][3])); \
        float mx = fmaxf(fmaxf(mj[0], mj[1]), fmaxf(mj[2], mj[3]));             \
        mx = fmaxf(mx, __shfl_xor(mx, 16));                                     \
        mx = fmaxf(mx, __shfl_xor(mx, 32));                                     \
        if (!__all(mx <= m + 8.0f)) {                                           \
            const float mnew = fmaxf(m, mx);                                    \
            const float corr = exp2f(m - mnew);                                 \
            m = mnew;                                                           \
            l *= corr;                                                          \
            _Pragma("unroll")                                                   \
            for (int d = 0; d < 4; ++d)                                         \
                _Pragma("unroll")                                               \
                for (int r = 0; r < 4; ++r)                                     \
                    o[d][r] *= corr;                                            \
        }                                                                       \
        float rs = 0.f;                                                         \
        _Pragma("unroll")                                                       \
        for (int js = 0; js < 4; ++js) {                                        \
            float p0 = exp2f(st[js][0] - m);                                    \
            float p1 = exp2f(st[js][1] - m);                                    \
            float p2 = exp2f(st[js][2] - m);                                    \
            float p3 = exp2f(st[js][3] - m);                                    \
            rs += (p0 + p1) + (p2 + p3);                                        \
            uint2 pk;                                                           \
            pk.x = cvt_pk_bf16(p0, p1);                                         \
            pk.y = cvt_pk_bf16(p2, p3);                                         \
            *(uint2*)&Pb[w][ln][(((js*4 + g) ^ (lnm << 1)) << 2)] = pk;         \
        }                                                                       \
        rs += __shfl_xor(rs, 16);                                               \
        rs += __shfl_xor(rs, 32);                                               \
        l += rs;                                                                \
        __builtin_amdgcn_s_setprio(1);                                          \
        _Pragma("unroll")                                                       \
        for (int kh = 0; kh < 2; ++kh) {                                        \
            bf16x8 pfr = __builtin_bit_cast(bf16x8,                             \
                           *(const short8_t*)&Pb[w][ln][(((kh*4 + g) ^ lnm) << 3)]); \
            _Pragma("unroll")                                                   \
            for (int dsub = 0; dsub < 4; ++dsub) {                              \
                const ushort_t* vr = &VBUF[(dsub*16 + ln) * 64];                \
                bf16x8 va = __builtin_bit_cast(bf16x8,                          \
                              *(const short8_t*)(vr + ((kh*4 + g) ^ lnm)*8));   \
                o[dsub] = __builtin_amdgcn_mfma_f32_16x16x32_bf16(va, pfr, o[dsub], 0, 0, 0); \
            }                                                                   \
        }                                                                       \
        __builtin_amdgcn_s_setprio(0);                                          \
    }

    int t = 0;
    for (;;) {
        ATTN_BODY(Kb0, Vb0, Kb1, Vb1);
        if (++t == nt) break;
        ATTN_BODY(Kb1, Vb1, Kb0, Vb0);
        if (++t == nt) break;
    }
#undef ATTN_BODY

    // ---- epilogue: O[d][q=ln] / l -> merged[b, q, h*64+d] ----
    const float inv = 1.f / l;
    const int row = q0 + w*16 + ln;
    #pragma unroll
    for (int dsub = 0; dsub < 4; ++dsub) {
        ushort4_t ov;
        ov[0] = f2bf(o[dsub][0] * inv);
        ov[1] = f2bf(o[dsub][1] * inv);
        ov[2] = f2bf(o[dsub][2] * inv);
        ov[3] = f2bf(o[dsub][3] * inv);
        *(ushort4_t*)&merged[((size_t)b * S_ + row) * D_ + h*64 + dsub*16 + g*4] = ov;
    }
}

// =====================================================================
extern "C" void kernel_launch(void* const* d_in, const int* in_sizes, int n_in,
                              void* d_out, int out_size, void* d_ws, size_t ws_size,
                              hipStream_t stream)
{
    const float* x      = (const float*)d_in[0];
    // d_in[1] = mask: causal structure computed analytically, never read
    const float* past   = (const float*)d_in[2];
    const float* w_attn = (const float*)d_in[3];
    const float* b_attn = (const float*)d_in[4];
    const float* w_proj = (const float*)d_in[5];
    const float* b_proj = (const float*)d_in[6];

    float* out     = (float*)d_out;                    // [B,S,D]
    float* present = out + (size_t)B_ * S_ * D_;       // [B,2,H,T,64]

    // ws layout (ushorts)
    ushort_t* wsu     = (ushort_t*)d_ws;
    ushort_t* q_ws    = wsu;                  // [B,H,S,64]   8 MB
    ushort_t* mergedb = wsu + 4194304;        // [4096][1024] 8 MB
    ushort_t* wptb    = wsu + 8388608;        // [1024][1024] 2 MB
    ushort_t* xb      = wsu + 9437184;        // [4096][1024] 8 MB (dead after gemm0)
    ushort_t* watb    = wsu + 13631488;       // [3072][1024] 6 MB (dead after gemm0)
    ushort_t* K_ws    = wsu + 9437184;        // overlays xb/watb: [32][T][64] 16 MB
    ushort_t* V_ws    = wsu + 17825792;       // [32][64][T] 16 MB

    // 0) prep
    convert_bf16_kernel<<<2048, 256, 0, stream>>>(
        (const float4*)x, (ushort4_t*)xb, (B_*S_*D_)/4);
    transpose_conv_kernel<<<dim3(48, 16), 256, 0, stream>>>(w_attn, watb, 3072);
    transpose_conv_kernel<<<dim3(16, 16), 256, 0, stream>>>(w_proj, wptb, 1024);

    // 1) QKV projection; q (exp2-domain pre-scaled) -> bf16 ws, k/v -> present f32
    gemm_bf16_kernel<0><<<dim3(24, 32), 256, 0, stream>>>(
        xb, watb, b_attn, q_ws, present, nullptr);

    // 2) fused: past->present (old rows) + present -> bf16 K_ws + V_ws^T
    prep_kv_kernel<<<dim3(64, 32), 256, 0, stream>>>(past, present, K_ws, V_ws);

    // 3) flash attention v7 -> merged bf16
    attn_v7_kernel<<<dim3(1024), 256, 0, stream>>>(q_ws, K_ws, V_ws, mergedb);

    // 4) output projection
    gemm_bf16_kernel<1><<<dim3(8, 32), 256, 0, stream>>>(
        mergedb, wptb, b_proj, nullptr, nullptr, out);
}

// Round 11
// 207.035 us; speedup vs baseline: 1.1186x; 1.0129x over previous
//
#include <hip/hip_runtime.h>
#include <hip/hip_bf16.h>

// Problem constants
#define B_ 2
#define S_ 2048
#define D_ 1024
#define H_ 16
#define P_ 2048
#define T_ 4096   // P_ + S_
#define DEPTH_ 64

typedef __bf16 bf16x8 __attribute__((ext_vector_type(8)));
typedef float  f32x4  __attribute__((ext_vector_type(4)));
typedef short  short8_t __attribute__((ext_vector_type(8)));
typedef unsigned short ushort_t;
typedef unsigned short ushort4_t __attribute__((ext_vector_type(4)));

// f32 -> bf16 round-to-nearest-even (cold paths)
__device__ __forceinline__ ushort_t f2bf(float f) {
    union { float f; unsigned u; } v; v.f = f;
    return (ushort_t)((v.u + 0x7fffu + ((v.u >> 16) & 1u)) >> 16);
}

// packed pair f32 -> 2x bf16 in one u32 (hot path; no builtin on gfx950)
__device__ __forceinline__ unsigned cvt_pk_bf16(float lo, float hi) {
    unsigned r;
    asm("v_cvt_pk_bf16_f32 %0, %1, %2" : "=v"(r) : "v"(lo), "v"(hi));
    return r;
}

__device__ __forceinline__ void gload16(const void* g, void* l) {
    __builtin_amdgcn_global_load_lds(
        (const __attribute__((address_space(1))) unsigned int*)g,
        (__attribute__((address_space(3))) unsigned int*)l, 16, 0, 0);
}

// =====================================================================
// x [4096][1024] f32 -> bf16
// =====================================================================
__global__ __launch_bounds__(256)
void convert_bf16_kernel(const float4* __restrict__ in, ushort4_t* __restrict__ out, int n4)
{
    for (int i = blockIdx.x * 256 + threadIdx.x; i < n4; i += gridDim.x * 256) {
        float4 v = in[i];
        ushort4_t o;
        o[0] = f2bf(v.x); o[1] = f2bf(v.y); o[2] = f2bf(v.z); o[3] = f2bf(v.w);
        out[i] = o;
    }
}

// =====================================================================
// w [K=1024][N] f32 -> wt [N][1024] bf16 (transposed)
// =====================================================================
__global__ __launch_bounds__(256)
void transpose_conv_kernel(const float* __restrict__ w, ushort_t* __restrict__ wt, int N)
{
    __shared__ float t[64][65];
    const int tid = threadIdx.x;
    const int k0 = blockIdx.y * 64, n0 = blockIdx.x * 64;
    #pragma unroll
    for (int rep = 0; rep < 4; ++rep) {
        const int idx = rep * 256 + tid;
        const int r = idx >> 4, c = idx & 15;
        float4 v = *(const float4*)&w[(size_t)(k0 + r) * N + n0 + c * 4];
        t[r][c*4+0] = v.x; t[r][c*4+1] = v.y; t[r][c*4+2] = v.z; t[r][c*4+3] = v.w;
    }
    __syncthreads();
    #pragma unroll
    for (int rep = 0; rep < 4; ++rep) {
        const int idx = rep * 256 + tid;
        const int nl = idx >> 4, kg = idx & 15;
        ushort4_t o;
        o[0] = f2bf(t[kg*4+0][nl]); o[1] = f2bf(t[kg*4+1][nl]);
        o[2] = f2bf(t[kg*4+2][nl]); o[3] = f2bf(t[kg*4+3][nl]);
        *(ushort4_t*)&wt[(size_t)(n0 + nl) * 1024 + k0 + kg*4] = o;
    }
}

// =====================================================================
// bf16 MFMA GEMM (m97 structure).
// MODE 0 scales q by 1/sqrt(64) * log2(e)  (exp2-domain softmax).
// =====================================================================
template<int MODE>
__global__ __launch_bounds__(256)
void gemm_bf16_kernel(const ushort_t* __restrict__ A,
                      const ushort_t* __restrict__ Bt,
                      const float*  __restrict__ bias,
                      ushort_t* __restrict__ out_qb,
                      float*  __restrict__ out_present,
                      float*  __restrict__ out_plain)
{
    __shared__ __attribute__((aligned(16))) ushort_t As[128*32];
    __shared__ __attribute__((aligned(16))) ushort_t Bs[128*32];

    const int tid  = threadIdx.x;
    const int w    = tid >> 6;
    const int lane = tid & 63;
    const int g    = lane >> 4;
    const int ln   = lane & 15;
    const int wr   = w >> 1, wc = w & 1;
    const int row0 = blockIdx.y * 128;
    const int col0 = blockIdx.x * 128;

    int srow[2], sgl[2];
    #pragma unroll
    for (int r = 0; r < 2; ++r) {
        const int o = (w*2 + r) * 1024 + lane * 16;
        srow[r] = o >> 6;
        const int gp = (o >> 4) & 3;
        sgl[r] = gp ^ ((srow[r] >> 1) & 3);
    }

    f32x4 acc[4][4];
    #pragma unroll
    for (int i = 0; i < 4; ++i)
        #pragma unroll
        for (int j = 0; j < 4; ++j)
            acc[i][j] = (f32x4){0.f, 0.f, 0.f, 0.f};

    for (int k0 = 0; k0 < 1024; k0 += 32) {
        #pragma unroll
        for (int r = 0; r < 2; ++r) {
            const int lb = (w*2 + r) * 512;
            gload16(&A [(size_t)(row0 + srow[r]) * 1024 + k0 + sgl[r]*8], &As[lb]);
            gload16(&Bt[(size_t)(col0 + srow[r]) * 1024 + k0 + sgl[r]*8], &Bs[lb]);
        }
        __syncthreads();

        bf16x8 af[4], bfr[4];
        #pragma unroll
        for (int i = 0; i < 4; ++i) {
            const int ra = wr*64 + i*16 + ln;
            const int ga = g ^ ((ra >> 1) & 3);
            af[i] = __builtin_bit_cast(bf16x8, *(const short8_t*)&As[ra*32 + ga*8]);
            const int rb = wc*64 + i*16 + ln;
            const int gb = g ^ ((rb >> 1) & 3);
            bfr[i] = __builtin_bit_cast(bf16x8, *(const short8_t*)&Bs[rb*32 + gb*8]);
        }
        #pragma unroll
        for (int i = 0; i < 4; ++i)
            #pragma unroll
            for (int j = 0; j < 4; ++j)
                acc[i][j] = __builtin_amdgcn_mfma_f32_16x16x32_bf16(af[i], bfr[j], acc[i][j], 0, 0, 0);
        __syncthreads();
    }

    #pragma unroll
    for (int i = 0; i < 4; ++i) {
        #pragma unroll
        for (int j = 0; j < 4; ++j) {
            const int rm = row0 + wr*64 + i*16 + g*4 + j;
            const int b  = rm >> 11;
            const int s  = rm & 2047;
            #pragma unroll
            for (int jn = 0; jn < 4; ++jn) {
                const int e = col0 + wc*64 + jn*16 + ln;
                const float v = acc[i][jn][j] + bias[e];
                if (MODE == 0) {
                    const int which = e >> 10;
                    const int f = e & 1023;
                    const int h = f >> 6, d = f & 63;
                    if (which == 0) {
                        // fold 1/sqrt(depth) * log2(e) into q (exp2 softmax)
                        out_qb[(size_t)(((b*16 + h) * 2048 + s) << 6) + d] =
                            f2bf(v * 0.18033688f);
                    } else {
                        const int kv = which - 1;
                        out_present[((((size_t)(b*2 + kv)*16 + h) * 4096 + 2048 + s) << 6) + d] = v;
                    }
                } else {
                    out_plain[(size_t)rm * 1024 + e] = v;
                }
            }
        }
    }
}

// =====================================================================
// Fused: past -> present (old rows, f32) + present -> K_ws/V_ws bf16.
// =====================================================================
__global__ __launch_bounds__(256)
void prep_kv_kernel(const float* __restrict__ past,
                    float* __restrict__ present,
                    ushort_t* __restrict__ Kws, ushort_t* __restrict__ Vws)
{
    __shared__ float tv[64][65];
    const int tid = threadIdx.x;
    const int kt  = blockIdx.x;       // 0..63
    const int bh  = blockIdx.y;       // 0..31
    const int b   = bh >> 4, h = bh & 15;
    const bool old = (kt < 32);

    const float* Kp = old ? past    + (((size_t)(b*2+0)*16 + h) * P_ + kt*64) * 64
                          : present + (((size_t)(b*2+0)*16 + h) * T_ + kt*64) * 64;
    const float* Vp = old ? past    + (((size_t)(b*2+1)*16 + h) * P_ + kt*64) * 64
                          : present + (((size_t)(b*2+1)*16 + h) * T_ + kt*64) * 64;
    float4* PKo = (float4*)(present + (((size_t)(b*2+0)*16 + h) * T_ + kt*64) * 64);
    float4* PVo = (float4*)(present + (((size_t)(b*2+1)*16 + h) * T_ + kt*64) * 64);
    ushort_t* Kd = Kws + ((size_t)bh * T_ + kt*64) * 64;

    #pragma unroll
    for (int rep = 0; rep < 4; ++rep) {
        const int idx = rep * 256 + tid;          // 0..1023 float4s
        float4 v = ((const float4*)Kp)[idx];
        if (old) PKo[idx] = v;
        ushort4_t o;
        o[0] = f2bf(v.x); o[1] = f2bf(v.y); o[2] = f2bf(v.z); o[3] = f2bf(v.w);
        *(ushort4_t*)&Kd[idx*4] = o;
        float4 vv = ((const float4*)Vp)[idx];
        if (old) PVo[idx] = vv;
        const int r = idx >> 4, c = idx & 15;
        tv[r][c*4+0] = vv.x; tv[r][c*4+1] = vv.y;
        tv[r][c*4+2] = vv.z; tv[r][c*4+3] = vv.w;
    }
    __syncthreads();
    #pragma unroll
    for (int rep = 0; rep < 4; ++rep) {
        const int idx = rep * 256 + tid;
        const int d = idx >> 4, pg = idx & 15;
        ushort4_t o;
        o[0] = f2bf(tv[pg*4+0][d]); o[1] = f2bf(tv[pg*4+1][d]);
        o[2] = f2bf(tv[pg*4+2][d]); o[3] = f2bf(tv[pg*4+3][d]);
        *(ushort4_t*)&Vws[((size_t)bh*64 + d) * T_ + kt*64 + pg*4] = o;
    }
}

// =====================================================================
// Flash attention v8 = v7 + P^T aliased into the CURRENT K buffer
// (dead after QK^T; prefetch targets the other buffer), guarded by one
// extra s_barrier between the QK^T LDS reads and the P writes.
// LDS drops 40960 -> 32768 B => 4 blocks/CU fit with headroom (cap 5).
// Mapping unchanged: XCD-local bh, CU-balanced qblk.
// =====================================================================
__global__ __launch_bounds__(256, 4)
void attn_v8_kernel(const ushort_t* __restrict__ qin,   // [B,H,S,64] bf16 (pre-scaled, log2 domain)
                    const ushort_t* __restrict__ Kws,   // [bh][T][64] bf16
                    const ushort_t* __restrict__ Vws,   // [bh][64][T] bf16
                    ushort_t* __restrict__ merged)      // [B,S,D] bf16
{
    __shared__ __attribute__((aligned(16))) ushort_t Kb0[4096];   // K tile buf0 [64][64]; P^T after QK^T
    __shared__ __attribute__((aligned(16))) ushort_t Kb1[4096];   // K tile buf1; P^T after QK^T
    __shared__ __attribute__((aligned(16))) ushort_t Vb0[4096];   // V^T tile buf0 [64 d][64 key]
    __shared__ __attribute__((aligned(16))) ushort_t Vb1[4096];   // V^T tile buf1

    const int tid  = threadIdx.x;
    const int w    = tid >> 6;
    const int lane = tid & 63;
    const int g    = lane >> 4;
    const int ln   = lane & 15;
    const int lnm  = ln & 7;
    const int lsub = lane >> 3;
    const int swz8 = ((lane & 7) ^ lsub) * 8;   // staging source granule swizzle

    // XCD-local + CU-balanced mapping
    const int bid = (int)blockIdx.x;
    const int a   = bid & 7;            // XCD slot
    const int m_c = (bid >> 3) & 31;    // CU within XCD
    const int j   = bid >> 8;           // resident slot on that CU
    const int bh  = a * 4 + (m_c & 3);
    const int c   = m_c >> 2;
    const int qblk = (j == 0) ? c : (j == 1) ? (15 - c) : (j == 2) ? (16 + c) : (31 - c);
    const int q0   = qblk * 64;
    const int b    = bh >> 4, h = bh & 15;

    const ushort_t* Kbase = Kws + (size_t)bh * T_ * 64;
    const ushort_t* Vbase = Vws + (size_t)bh * 64 * T_;
    const int nt = 33 + qblk;

    // hoisted staging offsets (loop-invariant)
    const int kgOff0 = ((w*16 + 0 + lsub) << 6) + swz8;      // rep 0 row offset
    const int kgOff1 = ((w*16 + 8 + lsub) << 6) + swz8;      // rep 1
    const size_t vgOff0 = (size_t)(w*16 + 0 + lsub) * T_ + swz8;
    const size_t vgOff1 = (size_t)(w*16 + 8 + lsub) * T_ + swz8;
    const int ldsOff0 = (w*2 + 0) * 512;
    const int ldsOff1 = (w*2 + 1) * 512;
    // P^T region inside current K buffer: row w*16+ln (128 B rows)
    const int pRow = (w*16 + ln) * 64;

    // prologue: stage tile 0 into buf 0
    gload16(Kbase + kgOff0, &Kb0[ldsOff0]);
    gload16(Kbase + kgOff1, &Kb0[ldsOff1]);
    gload16(Vbase + vgOff0, &Vb0[ldsOff0]);
    gload16(Vbase + vgOff1, &Vb0[ldsOff1]);

    // Q B-frags: col q = ln, k = d = kh*32 + g*8 + e
    bf16x8 qf[2];
    {
        const ushort_t* Qr = qin + ((size_t)bh * S_ + q0 + w*16 + ln) * 64;
        #pragma unroll
        for (int kh = 0; kh < 2; ++kh)
            qf[kh] = __builtin_bit_cast(bf16x8, *(const short8_t*)(Qr + kh*32 + g*8));
    }

    f32x4 o[4];      // O^T: o[dsub][r] = O[d=dsub*16+g*4+r][q=ln]
    #pragma unroll
    for (int d = 0; d < 4; ++d) o[d] = (f32x4){0.f, 0.f, 0.f, 0.f};
    float m = -3.0e38f, l = 0.f;

#define ATTN_BODY(KBUF, VBUF, NBUF_K, NBUF_V)                                   \
    {                                                                           \
        asm volatile("s_waitcnt vmcnt(0)" ::: "memory");                        \
        __builtin_amdgcn_s_barrier();                                           \
        __builtin_amdgcn_sched_barrier(0);                                      \
        if (t + 1 < nt) {                                                       \
            const size_t t0n = (size_t)(t + 1) * 64;                            \
            gload16(Kbase + (t0n << 6) + kgOff0, &NBUF_K[ldsOff0]);             \
            gload16(Kbase + (t0n << 6) + kgOff1, &NBUF_K[ldsOff1]);             \
            gload16(Vbase + vgOff0 + t0n, &NBUF_V[ldsOff0]);                    \
            gload16(Vbase + vgOff1 + t0n, &NBUF_V[ldsOff1]);                    \
            __builtin_amdgcn_sched_barrier(0);                                  \
        }                                                                       \
        f32x4 st[4];                                                            \
        __builtin_amdgcn_s_setprio(1);                                          \
        _Pragma("unroll")                                                       \
        for (int js = 0; js < 4; ++js) {                                        \
            const ushort_t* kr = &KBUF[(js*16 + ln) * 64];                      \
            bf16x8 a0 = __builtin_bit_cast(bf16x8, *(const short8_t*)(kr + ((    g) ^ lnm)*8)); \
            bf16x8 a1 = __builtin_bit_cast(bf16x8, *(const short8_t*)(kr + ((4 + g) ^ lnm)*8)); \
            f32x4 z = (f32x4){0.f, 0.f, 0.f, 0.f};                              \
            z = __builtin_amdgcn_mfma_f32_16x16x32_bf16(a0, qf[0], z, 0, 0, 0); \
            z = __builtin_amdgcn_mfma_f32_16x16x32_bf16(a1, qf[1], z, 0, 0, 0); \
            st[js] = z;                                                         \
        }                                                                       \
        __builtin_amdgcn_s_setprio(0);                                          \
        if (t == nt - 1) {                                                      \
            const int qr = w*16 + ln;                                           \
            _Pragma("unroll")                                                   \
            for (int js = 0; js < 4; ++js)                                      \
                _Pragma("unroll")                                               \
                for (int r = 0; r < 4; ++r)                                     \
                    if (js*16 + g*4 + r > qr) st[js][r] = -1e30f;               \
        }                                                                       \
        float mj[4];                                                            \
        _Pragma("unroll")                                                       \
        for (int js = 0; js < 4; ++js)                                          \
            mj[js] = fmaxf(fmaxf(st[js][0], st[js][1]), fmaxf(st[js][2], st[js][3])); \
        float mx = fmaxf(fmaxf(mj[0], mj[1]), fmaxf(mj[2], mj[3]));             \
        mx = fmaxf(mx, __shfl_xor(mx, 16));                                     \
        mx = fmaxf(mx, __shfl_xor(mx, 32));                                     \
        if (!__all(mx <= m + 8.0f)) {                                           \
            const float mnew = fmaxf(m, mx);                                    \
            const float corr = exp2f(m - mnew);                                 \
            m = mnew;                                                           \
            l *= corr;                                                          \
            _Pragma("unroll")                                                   \
            for (int d = 0; d < 4; ++d)                                         \
                _Pragma("unroll")                                               \
                for (int r = 0; r < 4; ++r)                                     \
                    o[d][r] *= corr;                                            \
        }                                                                       \
        /* all waves done reading KBUF (QK^T) -> safe to overwrite with P^T */  \
        __builtin_amdgcn_s_barrier();                                           \
        float rs = 0.f;                                                         \
        _Pragma("unroll")                                                       \
        for (int js = 0; js < 4; ++js) {                                        \
            float p0 = exp2f(st[js][0] - m);                                    \
            float p1 = exp2f(st[js][1] - m);                                    \
            float p2 = exp2f(st[js][2] - m);                                    \
            float p3 = exp2f(st[js][3] - m);                                    \
            rs += (p0 + p1) + (p2 + p3);                                        \
            uint2 pk;                                                           \
            pk.x = cvt_pk_bf16(p0, p1);                                         \
            pk.y = cvt_pk_bf16(p2, p3);                                         \
            *(uint2*)&KBUF[pRow + (((js*4 + g) ^ (lnm << 1)) << 2)] = pk;       \
        }                                                                       \
        rs += __shfl_xor(rs, 16);                                               \
        rs += __shfl_xor(rs, 32);                                               \
        l += rs;                                                                \
        __builtin_amdgcn_s_setprio(1);                                          \
        _Pragma("unroll")                                                       \
        for (int kh = 0; kh < 2; ++kh) {                                        \
            bf16x8 pfr = __builtin_bit_cast(bf16x8,                             \
                           *(const short8_t*)&KBUF[pRow + (((kh*4 + g) ^ lnm) << 3)]); \
            _Pragma("unroll")                                                   \
            for (int dsub = 0; dsub < 4; ++dsub) {                              \
                const ushort_t* vr = &VBUF[(dsub*16 + ln) * 64];                \
                bf16x8 va = __builtin_bit_cast(bf16x8,                          \
                              *(const short8_t*)(vr + ((kh*4 + g) ^ lnm)*8));   \
                o[dsub] = __builtin_amdgcn_mfma_f32_16x16x32_bf16(va, pfr, o[dsub], 0, 0, 0); \
            }                                                                   \
        }                                                                       \
        __builtin_amdgcn_s_setprio(0);                                          \
    }

    int t = 0;
    for (;;) {
        ATTN_BODY(Kb0, Vb0, Kb1, Vb1);
        if (++t == nt) break;
        ATTN_BODY(Kb1, Vb1, Kb0, Vb0);
        if (++t == nt) break;
    }
#undef ATTN_BODY

    // ---- epilogue: O[d][q=ln] / l -> merged[b, q, h*64+d] ----
    const float inv = 1.f / l;
    const int row = q0 + w*16 + ln;
    #pragma unroll
    for (int dsub = 0; dsub < 4; ++dsub) {
        ushort4_t ov;
        ov[0] = f2bf(o[dsub][0] * inv);
        ov[1] = f2bf(o[dsub][1] * inv);
        ov[2] = f2bf(o[dsub][2] * inv);
        ov[3] = f2bf(o[dsub][3] * inv);
        *(ushort4_t*)&merged[((size_t)b * S_ + row) * D_ + h*64 + dsub*16 + g*4] = ov;
    }
}

// =====================================================================
extern "C" void kernel_launch(void* const* d_in, const int* in_sizes, int n_in,
                              void* d_out, int out_size, void* d_ws, size_t ws_size,
                              hipStream_t stream)
{
    const float* x      = (const float*)d_in[0];
    // d_in[1] = mask: causal structure computed analytically, never read
    const float* past   = (const float*)d_in[2];
    const float* w_attn = (const float*)d_in[3];
    const float* b_attn = (const float*)d_in[4];
    const float* w_proj = (const float*)d_in[5];
    const float* b_proj = (const float*)d_in[6];

    float* out     = (float*)d_out;                    // [B,S,D]
    float* present = out + (size_t)B_ * S_ * D_;       // [B,2,H,T,64]

    // ws layout (ushorts)
    ushort_t* wsu     = (ushort_t*)d_ws;
    ushort_t* q_ws    = wsu;                  // [B,H,S,64]   8 MB
    ushort_t* mergedb = wsu + 4194304;        // [4096][1024] 8 MB
    ushort_t* wptb    = wsu + 8388608;        // [1024][1024] 2 MB
    ushort_t* xb      = wsu + 9437184;        // [4096][1024] 8 MB (dead after gemm0)
    ushort_t* watb    = wsu + 13631488;       // [3072][1024] 6 MB (dead after gemm0)
    ushort_t* K_ws    = wsu + 9437184;        // overlays xb/watb: [32][T][64] 16 MB
    ushort_t* V_ws    = wsu + 17825792;       // [32][64][T] 16 MB

    // 0) prep
    convert_bf16_kernel<<<2048, 256, 0, stream>>>(
        (const float4*)x, (ushort4_t*)xb, (B_*S_*D_)/4);
    transpose_conv_kernel<<<dim3(48, 16), 256, 0, stream>>>(w_attn, watb, 3072);
    transpose_conv_kernel<<<dim3(16, 16), 256, 0, stream>>>(w_proj, wptb, 1024);

    // 1) QKV projection; q (exp2-domain pre-scaled) -> bf16 ws, k/v -> present f32
    gemm_bf16_kernel<0><<<dim3(24, 32), 256, 0, stream>>>(
        xb, watb, b_attn, q_ws, present, nullptr);

    // 2) fused: past->present (old rows) + present -> bf16 K_ws + V_ws^T
    prep_kv_kernel<<<dim3(64, 32), 256, 0, stream>>>(past, present, K_ws, V_ws);

    // 3) flash attention v8 -> merged bf16
    attn_v8_kernel<<<dim3(1024), 256, 0, stream>>>(q_ws, K_ws, V_ws, mergedb);

    // 4) output projection
    gemm_bf16_kernel<1><<<dim3(8, 32), 256, 0, stream>>>(
        mergedb, wptb, b_proj, nullptr, nullptr, out);
}

// Round 12
// 200.941 us; speedup vs baseline: 1.1526x; 1.0303x over previous
//
#include <hip/hip_runtime.h>
#include <hip/hip_bf16.h>

// Problem constants
#define B_ 2
#define S_ 2048
#define D_ 1024
#define H_ 16
#define P_ 2048
#define T_ 4096   // P_ + S_
#define DEPTH_ 64

typedef __bf16 bf16x8 __attribute__((ext_vector_type(8)));
typedef float  f32x4  __attribute__((ext_vector_type(4)));
typedef short  short8_t __attribute__((ext_vector_type(8)));
typedef unsigned short ushort_t;
typedef unsigned short ushort4_t __attribute__((ext_vector_type(4)));

// f32 -> bf16 round-to-nearest-even (cold paths)
__device__ __forceinline__ ushort_t f2bf(float f) {
    union { float f; unsigned u; } v; v.f = f;
    return (ushort_t)((v.u + 0x7fffu + ((v.u >> 16) & 1u)) >> 16);
}

// packed pair f32 -> 2x bf16 in one u32 (hot path; no builtin on gfx950)
__device__ __forceinline__ unsigned cvt_pk_bf16(float lo, float hi) {
    unsigned r;
    asm("v_cvt_pk_bf16_f32 %0, %1, %2" : "=v"(r) : "v"(lo), "v"(hi));
    return r;
}

__device__ __forceinline__ void gload16(const void* g, void* l) {
    __builtin_amdgcn_global_load_lds(
        (const __attribute__((address_space(1))) unsigned int*)g,
        (__attribute__((address_space(3))) unsigned int*)l, 16, 0, 0);
}

// =====================================================================
// x [4096][1024] f32 -> bf16
// =====================================================================
__global__ __launch_bounds__(256)
void convert_bf16_kernel(const float4* __restrict__ in, ushort4_t* __restrict__ out, int n4)
{
    for (int i = blockIdx.x * 256 + threadIdx.x; i < n4; i += gridDim.x * 256) {
        float4 v = in[i];
        ushort4_t o;
        o[0] = f2bf(v.x); o[1] = f2bf(v.y); o[2] = f2bf(v.z); o[3] = f2bf(v.w);
        out[i] = o;
    }
}

// =====================================================================
// w [K=1024][N] f32 -> wt [N][1024] bf16 (transposed)
// =====================================================================
__global__ __launch_bounds__(256)
void transpose_conv_kernel(const float* __restrict__ w, ushort_t* __restrict__ wt, int N)
{
    __shared__ float t[64][65];
    const int tid = threadIdx.x;
    const int k0 = blockIdx.y * 64, n0 = blockIdx.x * 64;
    #pragma unroll
    for (int rep = 0; rep < 4; ++rep) {
        const int idx = rep * 256 + tid;
        const int r = idx >> 4, c = idx & 15;
        float4 v = *(const float4*)&w[(size_t)(k0 + r) * N + n0 + c * 4];
        t[r][c*4+0] = v.x; t[r][c*4+1] = v.y; t[r][c*4+2] = v.z; t[r][c*4+3] = v.w;
    }
    __syncthreads();
    #pragma unroll
    for (int rep = 0; rep < 4; ++rep) {
        const int idx = rep * 256 + tid;
        const int nl = idx >> 4, kg = idx & 15;
        ushort4_t o;
        o[0] = f2bf(t[kg*4+0][nl]); o[1] = f2bf(t[kg*4+1][nl]);
        o[2] = f2bf(t[kg*4+2][nl]); o[3] = f2bf(t[kg*4+3][nl]);
        *(ushort4_t*)&wt[(size_t)(n0 + nl) * 1024 + k0 + kg*4] = o;
    }
}

// =====================================================================
// bf16 MFMA GEMM (m97 structure).
// MODE 0 scales q by 1/sqrt(64) * log2(e)  (exp2-domain softmax).
// =====================================================================
template<int MODE>
__global__ __launch_bounds__(256)
void gemm_bf16_kernel(const ushort_t* __restrict__ A,
                      const ushort_t* __restrict__ Bt,
                      const float*  __restrict__ bias,
                      ushort_t* __restrict__ out_qb,
                      float*  __restrict__ out_present,
                      float*  __restrict__ out_plain)
{
    __shared__ __attribute__((aligned(16))) ushort_t As[128*32];
    __shared__ __attribute__((aligned(16))) ushort_t Bs[128*32];

    const int tid  = threadIdx.x;
    const int w    = tid >> 6;
    const int lane = tid & 63;
    const int g    = lane >> 4;
    const int ln   = lane & 15;
    const int wr   = w >> 1, wc = w & 1;
    const int row0 = blockIdx.y * 128;
    const int col0 = blockIdx.x * 128;

    int srow[2], sgl[2];
    #pragma unroll
    for (int r = 0; r < 2; ++r) {
        const int o = (w*2 + r) * 1024 + lane * 16;
        srow[r] = o >> 6;
        const int gp = (o >> 4) & 3;
        sgl[r] = gp ^ ((srow[r] >> 1) & 3);
    }

    f32x4 acc[4][4];
    #pragma unroll
    for (int i = 0; i < 4; ++i)
        #pragma unroll
        for (int j = 0; j < 4; ++j)
            acc[i][j] = (f32x4){0.f, 0.f, 0.f, 0.f};

    for (int k0 = 0; k0 < 1024; k0 += 32) {
        #pragma unroll
        for (int r = 0; r < 2; ++r) {
            const int lb = (w*2 + r) * 512;
            gload16(&A [(size_t)(row0 + srow[r]) * 1024 + k0 + sgl[r]*8], &As[lb]);
            gload16(&Bt[(size_t)(col0 + srow[r]) * 1024 + k0 + sgl[r]*8], &Bs[lb]);
        }
        __syncthreads();

        bf16x8 af[4], bfr[4];
        #pragma unroll
        for (int i = 0; i < 4; ++i) {
            const int ra = wr*64 + i*16 + ln;
            const int ga = g ^ ((ra >> 1) & 3);
            af[i] = __builtin_bit_cast(bf16x8, *(const short8_t*)&As[ra*32 + ga*8]);
            const int rb = wc*64 + i*16 + ln;
            const int gb = g ^ ((rb >> 1) & 3);
            bfr[i] = __builtin_bit_cast(bf16x8, *(const short8_t*)&Bs[rb*32 + gb*8]);
        }
        #pragma unroll
        for (int i = 0; i < 4; ++i)
            #pragma unroll
            for (int j = 0; j < 4; ++j)
                acc[i][j] = __builtin_amdgcn_mfma_f32_16x16x32_bf16(af[i], bfr[j], acc[i][j], 0, 0, 0);
        __syncthreads();
    }

    #pragma unroll
    for (int i = 0; i < 4; ++i) {
        #pragma unroll
        for (int j = 0; j < 4; ++j) {
            const int rm = row0 + wr*64 + i*16 + g*4 + j;
            const int b  = rm >> 11;
            const int s  = rm & 2047;
            #pragma unroll
            for (int jn = 0; jn < 4; ++jn) {
                const int e = col0 + wc*64 + jn*16 + ln;
                const float v = acc[i][jn][j] + bias[e];
                if (MODE == 0) {
                    const int which = e >> 10;
                    const int f = e & 1023;
                    const int h = f >> 6, d = f & 63;
                    if (which == 0) {
                        // fold 1/sqrt(depth) * log2(e) into q (exp2 softmax)
                        out_qb[(size_t)(((b*16 + h) * 2048 + s) << 6) + d] =
                            f2bf(v * 0.18033688f);
                    } else {
                        const int kv = which - 1;
                        out_present[((((size_t)(b*2 + kv)*16 + h) * 4096 + 2048 + s) << 6) + d] = v;
                    }
                } else {
                    out_plain[(size_t)rm * 1024 + e] = v;
                }
            }
        }
    }
}

// =====================================================================
// Fused: past -> present (old rows, f32) + present -> K_ws/V_ws bf16.
// =====================================================================
__global__ __launch_bounds__(256)
void prep_kv_kernel(const float* __restrict__ past,
                    float* __restrict__ present,
                    ushort_t* __restrict__ Kws, ushort_t* __restrict__ Vws)
{
    __shared__ float tv[64][65];
    const int tid = threadIdx.x;
    const int kt  = blockIdx.x;       // 0..63
    const int bh  = blockIdx.y;       // 0..31
    const int b   = bh >> 4, h = bh & 15;
    const bool old = (kt < 32);

    const float* Kp = old ? past    + (((size_t)(b*2+0)*16 + h) * P_ + kt*64) * 64
                          : present + (((size_t)(b*2+0)*16 + h) * T_ + kt*64) * 64;
    const float* Vp = old ? past    + (((size_t)(b*2+1)*16 + h) * P_ + kt*64) * 64
                          : present + (((size_t)(b*2+1)*16 + h) * T_ + kt*64) * 64;
    float4* PKo = (float4*)(present + (((size_t)(b*2+0)*16 + h) * T_ + kt*64) * 64);
    float4* PVo = (float4*)(present + (((size_t)(b*2+1)*16 + h) * T_ + kt*64) * 64);
    ushort_t* Kd = Kws + ((size_t)bh * T_ + kt*64) * 64;

    #pragma unroll
    for (int rep = 0; rep < 4; ++rep) {
        const int idx = rep * 256 + tid;          // 0..1023 float4s
        float4 v = ((const float4*)Kp)[idx];
        if (old) PKo[idx] = v;
        ushort4_t o;
        o[0] = f2bf(v.x); o[1] = f2bf(v.y); o[2] = f2bf(v.z); o[3] = f2bf(v.w);
        *(ushort4_t*)&Kd[idx*4] = o;
        float4 vv = ((const float4*)Vp)[idx];
        if (old) PVo[idx] = vv;
        const int r = idx >> 4, c = idx & 15;
        tv[r][c*4+0] = vv.x; tv[r][c*4+1] = vv.y;
        tv[r][c*4+2] = vv.z; tv[r][c*4+3] = vv.w;
    }
    __syncthreads();
    #pragma unroll
    for (int rep = 0; rep < 4; ++rep) {
        const int idx = rep * 256 + tid;
        const int d = idx >> 4, pg = idx & 15;
        ushort4_t o;
        o[0] = f2bf(tv[pg*4+0][d]); o[1] = f2bf(tv[pg*4+1][d]);
        o[2] = f2bf(tv[pg*4+2][d]); o[3] = f2bf(tv[pg*4+3][d]);
        *(ushort4_t*)&Vws[((size_t)bh*64 + d) * T_ + kt*64 + pg*4] = o;
    }
}

// =====================================================================
// Flash attention v9 = v8 + (a) counted vmcnt (T4): top-of-tile waits
// only K (vmcnt(2)); V completion moves to the mid (P-alias) barrier
// (vmcnt(4) steady state, vmcnt(0) last tile) — never a full drain in
// the main loop; (b) per-tile cross-lane shfls removed: defer-max check
// is per-lane (m wave-uniform => equivalent), max-shfls only inside the
// rare rescale branch, l kept as per-lane partial reduced once in the
// epilogue; (c) max3-friendly max tree.
// =====================================================================
__global__ __launch_bounds__(256, 4)
void attn_v9_kernel(const ushort_t* __restrict__ qin,   // [B,H,S,64] bf16 (pre-scaled, log2 domain)
                    const ushort_t* __restrict__ Kws,   // [bh][T][64] bf16
                    const ushort_t* __restrict__ Vws,   // [bh][64][T] bf16
                    ushort_t* __restrict__ merged)      // [B,S,D] bf16
{
    __shared__ __attribute__((aligned(16))) ushort_t Kb0[4096];   // K tile buf0 [64][64]; P^T after QK^T
    __shared__ __attribute__((aligned(16))) ushort_t Kb1[4096];   // K tile buf1; P^T after QK^T
    __shared__ __attribute__((aligned(16))) ushort_t Vb0[4096];   // V^T tile buf0 [64 d][64 key]
    __shared__ __attribute__((aligned(16))) ushort_t Vb1[4096];   // V^T tile buf1

    const int tid  = threadIdx.x;
    const int w    = tid >> 6;
    const int lane = tid & 63;
    const int g    = lane >> 4;
    const int ln   = lane & 15;
    const int lnm  = ln & 7;
    const int lsub = lane >> 3;
    const int swz8 = ((lane & 7) ^ lsub) * 8;   // staging source granule swizzle

    // XCD-local + CU-balanced mapping
    const int bid = (int)blockIdx.x;
    const int a   = bid & 7;            // XCD slot
    const int m_c = (bid >> 3) & 31;    // CU within XCD
    const int j   = bid >> 8;           // resident slot on that CU
    const int bh  = a * 4 + (m_c & 3);
    const int c   = m_c >> 2;
    const int qblk = (j == 0) ? c : (j == 1) ? (15 - c) : (j == 2) ? (16 + c) : (31 - c);
    const int q0   = qblk * 64;
    const int b    = bh >> 4, h = bh & 15;

    const ushort_t* Kbase = Kws + (size_t)bh * T_ * 64;
    const ushort_t* Vbase = Vws + (size_t)bh * 64 * T_;
    const int nt = 33 + qblk;

    // hoisted staging offsets (loop-invariant)
    const int kgOff0 = ((w*16 + 0 + lsub) << 6) + swz8;      // rep 0 row offset
    const int kgOff1 = ((w*16 + 8 + lsub) << 6) + swz8;      // rep 1
    const size_t vgOff0 = (size_t)(w*16 + 0 + lsub) * T_ + swz8;
    const size_t vgOff1 = (size_t)(w*16 + 8 + lsub) * T_ + swz8;
    const int ldsOff0 = (w*2 + 0) * 512;
    const int ldsOff1 = (w*2 + 1) * 512;
    // P^T region inside current K buffer: row w*16+ln (128 B rows)
    const int pRow = (w*16 + ln) * 64;

    // prologue: stage tile 0 into buf 0 (order: K first, then V — the
    // counted-vmcnt ledger relies on this issue order)
    gload16(Kbase + kgOff0, &Kb0[ldsOff0]);
    gload16(Kbase + kgOff1, &Kb0[ldsOff1]);
    gload16(Vbase + vgOff0, &Vb0[ldsOff0]);
    gload16(Vbase + vgOff1, &Vb0[ldsOff1]);

    // Q B-frags: col q = ln, k = d = kh*32 + g*8 + e
    bf16x8 qf[2];
    {
        const ushort_t* Qr = qin + ((size_t)bh * S_ + q0 + w*16 + ln) * 64;
        #pragma unroll
        for (int kh = 0; kh < 2; ++kh)
            qf[kh] = __builtin_bit_cast(bf16x8, *(const short8_t*)(Qr + kh*32 + g*8));
    }

    f32x4 o[4];      // O^T: o[dsub][r] = O[d=dsub*16+g*4+r][q=ln]
    #pragma unroll
    for (int d = 0; d < 4; ++d) o[d] = (f32x4){0.f, 0.f, 0.f, 0.f};
    float m = -3.0e38f, l = 0.f;   // l = per-lane partial (this lane's 16 keys)

#define ATTN_BODY(KBUF, VBUF, NBUF_K, NBUF_V)                                   \
    {                                                                           \
        /* own K loads for tile t done (V may still be in flight) */            \
        asm volatile("s_waitcnt vmcnt(2)" ::: "memory");                        \
        __builtin_amdgcn_s_barrier();                                           \
        __builtin_amdgcn_sched_barrier(0);                                      \
        const bool haspf = (t + 1 < nt);                                        \
        if (haspf) {                                                            \
            const size_t t0n = (size_t)(t + 1) * 64;                            \
            gload16(Kbase + (t0n << 6) + kgOff0, &NBUF_K[ldsOff0]);             \
            gload16(Kbase + (t0n << 6) + kgOff1, &NBUF_K[ldsOff1]);             \
            gload16(Vbase + vgOff0 + t0n, &NBUF_V[ldsOff0]);                    \
            gload16(Vbase + vgOff1 + t0n, &NBUF_V[ldsOff1]);                    \
            __builtin_amdgcn_sched_barrier(0);                                  \
        }                                                                       \
        f32x4 st[4];                                                            \
        __builtin_amdgcn_s_setprio(1);                                          \
        _Pragma("unroll")                                                       \
        for (int js = 0; js < 4; ++js) {                                        \
            const ushort_t* kr = &KBUF[(js*16 + ln) * 64];                      \
            bf16x8 a0 = __builtin_bit_cast(bf16x8, *(const short8_t*)(kr + ((    g) ^ lnm)*8)); \
            bf16x8 a1 = __builtin_bit_cast(bf16x8, *(const short8_t*)(kr + ((4 + g) ^ lnm)*8)); \
            f32x4 z = (f32x4){0.f, 0.f, 0.f, 0.f};                              \
            z = __builtin_amdgcn_mfma_f32_16x16x32_bf16(a0, qf[0], z, 0, 0, 0); \
            z = __builtin_amdgcn_mfma_f32_16x16x32_bf16(a1, qf[1], z, 0, 0, 0); \
            st[js] = z;                                                         \
        }                                                                       \
        __builtin_amdgcn_s_setprio(0);                                          \
        if (t == nt - 1) {                                                      \
            const int qr = w*16 + ln;                                           \
            _Pragma("unroll")                                                   \
            for (int js = 0; js < 4; ++js)                                      \
                _Pragma("unroll")                                               \
                for (int r = 0; r < 4; ++r)                                     \
                    if (js*16 + g*4 + r > qr) st[js][r] = -1e30f;               \
        }                                                                       \
        /* per-lane max only; cross-lane deferred to rescale branch */          \
        float mj[4];                                                            \
        _Pragma("unroll")                                                       \
        for (int js = 0; js < 4; ++js) {                                        \
            float m01 = fmaxf(st[js][0], st[js][1]);                            \
            mj[js] = fmaxf(fmaxf(m01, st[js][2]), st[js][3]);                   \
        }                                                                       \
        float mx16 = fmaxf(fmaxf(fmaxf(mj[0], mj[1]), mj[2]), mj[3]);           \
        if (!__all(mx16 <= m + 8.0f)) {                                         \
            float gmx = fmaxf(mx16, __shfl_xor(mx16, 16));                      \
            gmx = fmaxf(gmx, __shfl_xor(gmx, 32));                              \
            const float mnew = fmaxf(m, gmx);                                   \
            const float corr = exp2f(m - mnew);                                 \
            m = mnew;                                                           \
            l *= corr;                                                          \
            _Pragma("unroll")                                                   \
            for (int d = 0; d < 4; ++d)                                         \
                _Pragma("unroll")                                               \
                for (int r = 0; r < 4; ++r)                                     \
                    o[d][r] *= corr;                                            \
        }                                                                       \
        /* V(t) done (steady: 4 of t+1 outstanding) + all QK^T reads done */    \
        if (haspf) { asm volatile("s_waitcnt vmcnt(4)" ::: "memory"); }         \
        else       { asm volatile("s_waitcnt vmcnt(0)" ::: "memory"); }         \
        __builtin_amdgcn_s_barrier();                                           \
        __builtin_amdgcn_sched_barrier(0);                                      \
        float rs = 0.f;                                                         \
        _Pragma("unroll")                                                       \
        for (int js = 0; js < 4; ++js) {                                        \
            float p0 = exp2f(st[js][0] - m);                                    \
            float p1 = exp2f(st[js][1] - m);                                    \
            float p2 = exp2f(st[js][2] - m);                                    \
            float p3 = exp2f(st[js][3] - m);                                    \
            rs += (p0 + p1) + (p2 + p3);                                        \
            uint2 pk;                                                           \
            pk.x = cvt_pk_bf16(p0, p1);                                         \
            pk.y = cvt_pk_bf16(p2, p3);                                         \
            *(uint2*)&KBUF[pRow + (((js*4 + g) ^ (lnm << 1)) << 2)] = pk;       \
        }                                                                       \
        l += rs;                                                                \
        __builtin_amdgcn_s_setprio(1);                                          \
        _Pragma("unroll")                                                       \
        for (int kh = 0; kh < 2; ++kh) {                                        \
            bf16x8 pfr = __builtin_bit_cast(bf16x8,                             \
                           *(const short8_t*)&KBUF[pRow + (((kh*4 + g) ^ lnm) << 3)]); \
            _Pragma("unroll")                                                   \
            for (int dsub = 0; dsub < 4; ++dsub) {                              \
                const ushort_t* vr = &VBUF[(dsub*16 + ln) * 64];                \
                bf16x8 va = __builtin_bit_cast(bf16x8,                          \
                              *(const short8_t*)(vr + ((kh*4 + g) ^ lnm)*8));   \
                o[dsub] = __builtin_amdgcn_mfma_f32_16x16x32_bf16(va, pfr, o[dsub], 0, 0, 0); \
            }                                                                   \
        }                                                                       \
        __builtin_amdgcn_s_setprio(0);                                          \
    }

    int t = 0;
    for (;;) {
        ATTN_BODY(Kb0, Vb0, Kb1, Vb1);
        if (++t == nt) break;
        ATTN_BODY(Kb1, Vb1, Kb0, Vb0);
        if (++t == nt) break;
    }
#undef ATTN_BODY

    // ---- epilogue: reduce per-lane l partials (once), then divide ----
    float lf = l + __shfl_xor(l, 16);
    lf = lf + __shfl_xor(lf, 32);
    const float inv = 1.f / lf;
    const int row = q0 + w*16 + ln;
    #pragma unroll
    for (int dsub = 0; dsub < 4; ++dsub) {
        ushort4_t ov;
        ov[0] = f2bf(o[dsub][0] * inv);
        ov[1] = f2bf(o[dsub][1] * inv);
        ov[2] = f2bf(o[dsub][2] * inv);
        ov[3] = f2bf(o[dsub][3] * inv);
        *(ushort4_t*)&merged[((size_t)b * S_ + row) * D_ + h*64 + dsub*16 + g*4] = ov;
    }
}

// =====================================================================
extern "C" void kernel_launch(void* const* d_in, const int* in_sizes, int n_in,
                              void* d_out, int out_size, void* d_ws, size_t ws_size,
                              hipStream_t stream)
{
    const float* x      = (const float*)d_in[0];
    // d_in[1] = mask: causal structure computed analytically, never read
    const float* past   = (const float*)d_in[2];
    const float* w_attn = (const float*)d_in[3];
    const float* b_attn = (const float*)d_in[4];
    const float* w_proj = (const float*)d_in[5];
    const float* b_proj = (const float*)d_in[6];

    float* out     = (float*)d_out;                    // [B,S,D]
    float* present = out + (size_t)B_ * S_ * D_;       // [B,2,H,T,64]

    // ws layout (ushorts)
    ushort_t* wsu     = (ushort_t*)d_ws;
    ushort_t* q_ws    = wsu;                  // [B,H,S,64]   8 MB
    ushort_t* mergedb = wsu + 4194304;        // [4096][1024] 8 MB
    ushort_t* wptb    = wsu + 8388608;        // [1024][1024] 2 MB
    ushort_t* xb      = wsu + 9437184;        // [4096][1024] 8 MB (dead after gemm0)
    ushort_t* watb    = wsu + 13631488;       // [3072][1024] 6 MB (dead after gemm0)
    ushort_t* K_ws    = wsu + 9437184;        // overlays xb/watb: [32][T][64] 16 MB
    ushort_t* V_ws    = wsu + 17825792;       // [32][64][T] 16 MB

    // 0) prep
    convert_bf16_kernel<<<2048, 256, 0, stream>>>(
        (const float4*)x, (ushort4_t*)xb, (B_*S_*D_)/4);
    transpose_conv_kernel<<<dim3(48, 16), 256, 0, stream>>>(w_attn, watb, 3072);
    transpose_conv_kernel<<<dim3(16, 16), 256, 0, stream>>>(w_proj, wptb, 1024);

    // 1) QKV projection; q (exp2-domain pre-scaled) -> bf16 ws, k/v -> present f32
    gemm_bf16_kernel<0><<<dim3(24, 32), 256, 0, stream>>>(
        xb, watb, b_attn, q_ws, present, nullptr);

    // 2) fused: past->present (old rows) + present -> bf16 K_ws + V_ws^T
    prep_kv_kernel<<<dim3(64, 32), 256, 0, stream>>>(past, present, K_ws, V_ws);

    // 3) flash attention v9 -> merged bf16
    attn_v9_kernel<<<dim3(1024), 256, 0, stream>>>(q_ws, K_ws, V_ws, mergedb);

    // 4) output projection
    gemm_bf16_kernel<1><<<dim3(8, 32), 256, 0, stream>>>(
        mergedb, wptb, b_proj, nullptr, nullptr, out);
}